// Round 15
// baseline (813.426 us; speedup 1.0000x reference)
//
#include <hip/hip_runtime.h>

#define HDIM  64
#define INDIM 7
#define QDIM  3
#define TDEC  288
#define SEQ   512
#define NB    2        // batches per block -> grid 1024 -> 4 blocks/CU at <=128 regs
#define CHUNK 32       // x timesteps staged per LDS chunk
#define HPAD  68       // fp32 h/c row stride (decoder handoff)
#define GPAD  264      // lds_g row stride (decoder gbase only)
#define HBST  80       // bf16 h row stride in shorts (160B)

typedef __attribute__((ext_vector_type(8))) short bf16x8;   // 8 bf16 in 4 VGPRs
typedef __attribute__((ext_vector_type(4))) float f32x4;

__device__ __forceinline__ float fast_rcp(float x) { return __builtin_amdgcn_rcpf(x); }
__device__ __forceinline__ float sigm(float x) { return fast_rcp(1.0f + __expf(-x)); }
__device__ __forceinline__ float tanh_f(float x) {
    float xx = fminf(fmaxf(x, -15.0f), 15.0f);
    float e = __expf(2.0f * xx);
    return (e - 1.0f) * fast_rcp(e + 1.0f);
}
// round-to-nearest-even fp32 -> bf16 bits (one-time paths)
__device__ __forceinline__ short f2bf(float f) {
    union { float f; unsigned u; } v; v.f = f;
    unsigned r = (v.u + 0x7fffu + ((v.u >> 16) & 1u)) >> 16;
    return (short)r;
}
__device__ __forceinline__ float bf2f(short s) {
    union { unsigned u; float f; } v; v.u = ((unsigned)(unsigned short)s) << 16;
    return v.f;
}

// R15: occupancy play. R11 structure (one barrier/step, lane-matched act,
// x@Wih on VALU) with two register cuts so 4 blocks/CU fit (128-reg budget):
//  - 2-pass MFMA: Whi*h_hi + Whi*h_lo (W bf16-quantized; drops a_lo = 32 VGPR,
//    MFMA 24->16/wave-step). Predicted absmax ~1e-3, under 3.24e-3 threshold.
//  - NB=2 -> grid 1024 gives the scheduler 4 resident blocks/CU.
// Act runs on lanes (lane&3)<2 (b = lane&1); coverage of all (b,u) exact.
__global__ __launch_bounds__(256, 4)
void enc_dec_kernel(const float* __restrict__ x,
                    const float* __restrict__ eWih, const float* __restrict__ eWhh,
                    const float* __restrict__ ebih, const float* __restrict__ ebhh,
                    const float* __restrict__ dWih, const float* __restrict__ dWhh,
                    const float* __restrict__ dbih, const float* __restrict__ dbhh,
                    const float* __restrict__ oW,   const float* __restrict__ obv,
                    float* __restrict__ out)
{
    __shared__ __align__(16) short lds_hhi[2][NB][HBST];   // h hi bf16, parity dbuf
    __shared__ __align__(16) short lds_hlo[2][NB][HBST];   // h lo bf16
    __shared__ __align__(16) float lds_hf[NB][HPAD];       // fp32 h_enc (final step)
    __shared__ __align__(16) float lds_cf[NB][HPAD];       // fp32 c_enc (final step)
    __shared__ __align__(16) float lds_g[NB][GPAD];        // decoder gbase staging
    __shared__ __align__(16) float lds_x[2][NB][CHUNK][8]; // fp32 x (b-stride 1024B: 2-way = free)

    const int tid  = threadIdx.x;
    const int lane = tid & 63;
    const int wid  = tid >> 6;
    const int b0   = blockIdx.x * NB;

    // act assignment: lanes with (lane&3)<2 act for b = lane&1,
    // u = wid*16 + (lane>>4)*4 + ((lane>>2)&3). Coverage exact per wave.
    const int b_act     = lane & 1;
    const bool act_on   = (lane & 3) < 2;
    const int rsel      = (lane >> 2) & 3;
    const int u_act     = wid * 16 + (lane >> 4) * 4 + rsel;

    // ---- A-fragments (hi only): M-tiles g*64 + wid*16, rows + (lane&15) ----
    bf16x8 a_hi[4][2];
    {
        const int m = lane & 15, g16 = lane >> 4;
#pragma unroll
        for (int g = 0; g < 4; ++g) {
#pragma unroll
            for (int kt = 0; kt < 2; ++kt) {
                const float* p = eWhh + (size_t)(g * 64 + wid * 16 + m) * HDIM + kt * 32 + g16 * 8;
                f32x4 v0 = *(const f32x4*)p;
                f32x4 v1 = *(const f32x4*)(p + 4);
#pragma unroll
                for (int e = 0; e < 4; ++e) a_hi[g][kt][e]     = f2bf(v0[e]);
#pragma unroll
                for (int e = 0; e < 4; ++e) a_hi[g][kt][4 + e] = f2bf(v1[e]);
            }
        }
    }

    // ---- act constants for rows g*64 + u_act ----
    float wih_r[4][7];
    float bias_r[4];
#pragma unroll
    for (int g = 0; g < 4; ++g) {
        const int r = g * 64 + u_act;
#pragma unroll
        for (int k = 0; k < 7; ++k) wih_r[g][k] = eWih[r * INDIM + k];
        bias_r[g] = ebih[r] + ebhh[r];
    }

    // ---- init: step 0 reads parity buffer 1 ----
    if (wid < NB) {
        lds_hhi[1][wid][lane] = 0;
        lds_hlo[1][wid][lane] = 0;
    }
    float c_reg = 0.0f;          // c for (b_act, u_act), valid where act_on

    // ---- load x chunk 0 ----
    for (int i = tid; i < NB * CHUNK * 8; i += 256) {
        int b = i >> 8;          // CHUNK*8 == 256
        int r = i & 255;
        int s = r >> 3;
        int k = r & 7;
        float v = 0.0f;
        if (k < 7) v = x[((size_t)(b0 + b) * SEQ + s) * INDIM + k];
        lds_x[0][b][s][k] = v;
    }
    __syncthreads();

    // ================= encoder: 512 serial steps, ONE barrier each =================
    for (int s = 0; s < SEQ; ++s) {
        const int cs  = s & (CHUNK - 1);
        const int buf = (s >> 5) & 1;
        const int rb  = (s & 1) ^ 1;   // h read-parity
        const int wb  = s & 1;         // h write-parity

        // ---- B fragments: b128 reads of pre-split bf16 h (cols replicate mod 2) ----
        bf16x8 bhi[2], blo[2];
        {
            const int bb = lane & 1, g16 = lane >> 4;
#pragma unroll
            for (int kt = 0; kt < 2; ++kt) {
                bhi[kt] = *(const bf16x8*)&lds_hhi[rb][bb][kt * 32 + g16 * 8];
                blo[kt] = *(const bf16x8*)&lds_hlo[rb][bb][kt * 32 + g16 * 8];
            }
        }

        // ---- MFMA: 2-pass (Whi*hhi + Whi*hlo), 4 independent acc chains ----
        f32x4 acc[4] = {{0,0,0,0},{0,0,0,0},{0,0,0,0},{0,0,0,0}};
#pragma unroll
        for (int kt = 0; kt < 2; ++kt) {
#pragma unroll
            for (int g = 0; g < 4; ++g)
                acc[g] = __builtin_amdgcn_mfma_f32_16x16x32_bf16(a_hi[g][kt], bhi[kt], acc[g], 0, 0, 0);
#pragma unroll
            for (int g = 0; g < 4; ++g)
                acc[g] = __builtin_amdgcn_mfma_f32_16x16x32_bf16(a_hi[g][kt], blo[kt], acc[g], 0, 0, 0);
        }

        // ---- extract this lane's r-slot via cndmask ----
        float pre[4];
#pragma unroll
        for (int g = 0; g < 4; ++g) {
            float s01 = (rsel & 1) ? acc[g][1] : acc[g][0];
            float s23 = (rsel & 1) ? acc[g][3] : acc[g][2];
            pre[g] = (rsel & 2) ? s23 : s01;
        }

        // ---- activation: lanes with (lane&3)<2 only ----
        if (act_on) {
            f32x4 x0 = *(const f32x4*)&lds_x[buf][b_act][cs][0];
            f32x4 x1 = *(const f32x4*)&lds_x[buf][b_act][cs][4];
#pragma unroll
            for (int g = 0; g < 4; ++g) {
                pre[g] += bias_r[g]
                        + x0[0] * wih_r[g][0] + x0[1] * wih_r[g][1] + x0[2] * wih_r[g][2]
                        + x0[3] * wih_r[g][3] + x1[0] * wih_r[g][4] + x1[1] * wih_r[g][5]
                        + x1[2] * wih_r[g][6];
            }
            float ig = sigm(pre[0]), fg = sigm(pre[1]), gg = tanh_f(pre[2]), og = sigm(pre[3]);
            c_reg = fg * c_reg + ig * gg;
            float h = og * tanh_f(c_reg);
            // truncation hi/lo split: r = h - trunc16(h) exact (Sterbenz)
            union { float f; unsigned u; } hu; hu.f = h;
            unsigned hib = hu.u >> 16;
            union { unsigned u; float f; } ht; ht.u = hu.u & 0xffff0000u;
            union { float f; unsigned u; } ru; ru.f = h - ht.f;
            unsigned lob = ru.u >> 16;
            lds_hhi[wb][b_act][u_act] = (short)hib;
            lds_hlo[wb][b_act][u_act] = (short)lob;
            if (s + 1 == SEQ) {
                lds_hf[b_act][u_act] = h;
                lds_cf[b_act][u_act] = c_reg;
            }
        }

        // ---- prefetch next x chunk ----
        if (cs == 0 && s + CHUNK < SEQ) {
            const int nbuf = buf ^ 1;
            const int s0n  = s + CHUNK;
            for (int i = tid; i < NB * CHUNK * 8; i += 256) {
                int b = i >> 8;
                int r = i & 255;
                int ss = r >> 3;
                int k = r & 7;
                float v = 0.0f;
                if (k < 7) v = x[((size_t)(b0 + b) * SEQ + (s0n + ss)) * INDIM + k];
                lds_x[nbuf][b][ss][k] = v;
            }
        }
        __syncthreads();   // h[wb] published for next step
    }
    // lds_hf/lds_cf hold h_enc/c_enc in (b, j) layout

    // ====== decoder gbase = b + h_enc @ dW_hh.T (fp32, one-time) ======
    {
        const int row = wid * HDIM + lane;
        float4 dwhh[16];
#pragma unroll
        for (int m4 = 0; m4 < 16; ++m4)
            dwhh[m4] = *reinterpret_cast<const float4*>(&dWhh[row * HDIM + m4 * 4]);
        const float dbias = dbih[row] + dbhh[row];

        float accd[NB];
#pragma unroll
        for (int b = 0; b < NB; ++b) accd[b] = dbias;
#pragma unroll
        for (int m4 = 0; m4 < 16; ++m4) {
            const float4 w = dwhh[m4];
            float4 hv[NB];
#pragma unroll
            for (int b = 0; b < NB; ++b)
                hv[b] = *reinterpret_cast<const float4*>(&lds_hf[b][m4 * 4]);
#pragma unroll
            for (int b = 0; b < NB; ++b) accd[b] = fmaf(hv[b].x, w.x, accd[b]);
#pragma unroll
            for (int b = 0; b < NB; ++b) accd[b] = fmaf(hv[b].y, w.y, accd[b]);
#pragma unroll
            for (int b = 0; b < NB; ++b) accd[b] = fmaf(hv[b].z, w.z, accd[b]);
#pragma unroll
            for (int b = 0; b < NB; ++b) accd[b] = fmaf(hv[b].w, w.w, accd[b]);
        }
#pragma unroll
        for (int b = 0; b < NB; ++b) lds_g[b][row] = accd[b];
    }
    __syncthreads();

    // ================= decoder: wave = one batch (waves 0..NB-1) =================
    if (wid < NB) {
        const int b = wid, j = lane;
        const float c_e = lds_cf[b][j];
        const float gb0 = lds_g[b][j];
        const float gb1 = lds_g[b][HDIM + j];
        const float gb2 = lds_g[b][2 * HDIM + j];
        const float gb3 = lds_g[b][3 * HDIM + j];

        const float w00 = dWih[(0 * HDIM + j) * QDIM + 0], w01 = dWih[(0 * HDIM + j) * QDIM + 1], w02 = dWih[(0 * HDIM + j) * QDIM + 2];
        const float w10 = dWih[(1 * HDIM + j) * QDIM + 0], w11 = dWih[(1 * HDIM + j) * QDIM + 1], w12 = dWih[(1 * HDIM + j) * QDIM + 2];
        const float w20 = dWih[(2 * HDIM + j) * QDIM + 0], w21 = dWih[(2 * HDIM + j) * QDIM + 1], w22 = dWih[(2 * HDIM + j) * QDIM + 2];
        const float w30 = dWih[(3 * HDIM + j) * QDIM + 0], w31 = dWih[(3 * HDIM + j) * QDIM + 1], w32 = dWih[(3 * HDIM + j) * QDIM + 2];
        const float ow0 = oW[0 * HDIM + j], ow1 = oW[1 * HDIM + j], ow2 = oW[2 * HDIM + j];
        const float ob0 = obv[0], ob1 = obv[1], ob2 = obv[2];

        float y0 = 0.0f, y1 = 0.0f, y2 = 0.0f;
        float* outp = out + (size_t)(b0 + b) * TDEC * QDIM;

        for (int t = 0; t < TDEC; ++t) {
            float g0 = gb0 + y0 * w00 + y1 * w01 + y2 * w02;
            float g1 = gb1 + y0 * w10 + y1 * w11 + y2 * w12;
            float g2 = gb2 + y0 * w20 + y1 * w21 + y2 * w22;
            float g3 = gb3 + y0 * w30 + y1 * w31 + y2 * w32;
            float ig = sigm(g0), fg = sigm(g1), gg = tanh_f(g2), og = sigm(g3);
            float c = fg * c_e + ig * gg;
            float h = og * tanh_f(c);
            float r0 = h * ow0, r1 = h * ow1, r2 = h * ow2;
#pragma unroll
            for (int d = 1; d < 64; d <<= 1) {
                r0 += __shfl_xor(r0, d);
                r1 += __shfl_xor(r1, d);
                r2 += __shfl_xor(r2, d);
            }
            y0 = r0 + ob0;
            y1 = r1 + ob1;
            y2 = r2 + ob2;
            if (j < QDIM) outp[t * QDIM + j] = (j == 0) ? y0 : (j == 1) ? y1 : y2;
        }
    }
}

extern "C" void kernel_launch(void* const* d_in, const int* in_sizes, int n_in,
                              void* d_out, int out_size, void* d_ws, size_t ws_size,
                              hipStream_t stream) {
    (void)in_sizes; (void)n_in; (void)d_ws; (void)ws_size; (void)out_size;
    const float* x    = (const float*)d_in[0];
    const float* eWih = (const float*)d_in[1];
    const float* eWhh = (const float*)d_in[2];
    const float* ebih = (const float*)d_in[3];
    const float* ebhh = (const float*)d_in[4];
    const float* dWih = (const float*)d_in[5];
    const float* dWhh = (const float*)d_in[6];
    const float* dbih = (const float*)d_in[7];
    const float* dbhh = (const float*)d_in[8];
    const float* oW   = (const float*)d_in[9];
    const float* obv  = (const float*)d_in[10];
    float* out = (float*)d_out;

    const int B = 2048;
    dim3 grid(B / NB), block(256);
    enc_dec_kernel<<<grid, block, 0, stream>>>(x, eWih, eWhh, ebih, ebhh,
                                               dWih, dWhh, dbih, dbhh, oW, obv, out);
}

// Round 16
// 608.441 us; speedup vs baseline: 1.3369x; 1.3369x over previous
//
#include <hip/hip_runtime.h>

#define HDIM  64
#define INDIM 7
#define QDIM  3
#define TDEC  288
#define SEQ   512
#define NBT   8        // batches per block -> grid 256 = 1 block/CU, no replication waste
#define CHUNK 32       // x timesteps staged per LDS chunk
#define HPAD  68       // fp32 h/c row stride (decoder handoff)
#define GPAD  264      // lds_g row stride (decoder gbase only)
#define HBST  80       // bf16 h row stride in shorts (160B)

typedef __attribute__((ext_vector_type(8))) short bf16x8;   // 8 bf16 in 4 VGPRs
typedef __attribute__((ext_vector_type(4))) float f32x4;

__device__ __forceinline__ float fast_rcp(float x) { return __builtin_amdgcn_rcpf(x); }
__device__ __forceinline__ float sigm(float x) { return fast_rcp(1.0f + __expf(-x)); }
__device__ __forceinline__ float tanh_f(float x) {
    float xx = fminf(fmaxf(x, -15.0f), 15.0f);
    float e = __expf(2.0f * xx);
    return (e - 1.0f) * fast_rcp(e + 1.0f);
}
// round-to-nearest-even fp32 -> bf16 bits (one-time paths)
__device__ __forceinline__ short f2bf(float f) {
    union { float f; unsigned u; } v; v.f = f;
    unsigned r = (v.u + 0x7fffu + ((v.u >> 16) & 1u)) >> 16;
    return (short)r;
}
__device__ __forceinline__ float bf2f(short s) {
    union { unsigned u; float f; } v; v.u = ((unsigned)(unsigned short)s) << 16;
    return v.f;
}

// R16: 8 batches/block (MFMA cols 0-15 = batches 0-7 x2) -> same 24 MFMA/wave
// serves 2x the batches; grid 256 = 1 block/CU; launch_bounds(256,1) = 512-reg
// budget, spill impossible. Lane L: acc[g][r] = gate g, b=L&7,
// u=wid*16+(L>>4)*4+r. Lane acts for TWO units u0,u0+1 (u0=..+2q, q=(L>>3)&1):
// extraction 1 cndmask/gate/chain, two independent act chains (ILP). h packed
// 2xbf16 per dword write. One barrier/step, parity dbuf. 3-pass hi/lo MFMA.
__global__ __launch_bounds__(256, 1)
void enc_dec_kernel(const float* __restrict__ x,
                    const float* __restrict__ eWih, const float* __restrict__ eWhh,
                    const float* __restrict__ ebih, const float* __restrict__ ebhh,
                    const float* __restrict__ dWih, const float* __restrict__ dWhh,
                    const float* __restrict__ dbih, const float* __restrict__ dbhh,
                    const float* __restrict__ oW,   const float* __restrict__ obv,
                    float* __restrict__ out)
{
    __shared__ __align__(16) short lds_hhi[2][NBT][HBST];    // h hi bf16, parity dbuf
    __shared__ __align__(16) short lds_hlo[2][NBT][HBST];    // h lo bf16
    __shared__ __align__(16) float lds_hf[NBT][HPAD];        // fp32 h_enc (final step)
    __shared__ __align__(16) float lds_cf[NBT][HPAD];        // fp32 c_enc (final step)
    __shared__ __align__(16) float lds_g[NBT][GPAD];         // decoder gbase staging
    __shared__ __align__(16) float lds_x[2][CHUNK][NBT][8];  // fp32 x, cs-major

    const int tid  = threadIdx.x;
    const int lane = tid & 63;
    const int wid  = tid >> 6;
    const int b0   = blockIdx.x * NBT;

    const int b_act = lane & 7;            // batch this lane's col carries
    const int q     = (lane >> 3) & 1;     // r-pair select
    const int u0    = wid * 16 + (lane >> 4) * 4 + q * 2;   // acts for u0, u0+1

    // ---- A-fragments: M-tiles g*64 + wid*16, rows + (lane&15); hi/lo bf16 ----
    bf16x8 a_hi[4][2], a_lo[4][2];
    {
        const int m = lane & 15, g16 = lane >> 4;
#pragma unroll
        for (int g = 0; g < 4; ++g) {
#pragma unroll
            for (int kt = 0; kt < 2; ++kt) {
                const float* p = eWhh + (size_t)(g * 64 + wid * 16 + m) * HDIM + kt * 32 + g16 * 8;
                f32x4 v0 = *(const f32x4*)p;
                f32x4 v1 = *(const f32x4*)(p + 4);
#pragma unroll
                for (int e = 0; e < 4; ++e) {
                    short hi = f2bf(v0[e]);
                    a_hi[g][kt][e] = hi;
                    a_lo[g][kt][e] = f2bf(v0[e] - bf2f(hi));
                }
#pragma unroll
                for (int e = 0; e < 4; ++e) {
                    short hi = f2bf(v1[e]);
                    a_hi[g][kt][4 + e] = hi;
                    a_lo[g][kt][4 + e] = f2bf(v1[e] - bf2f(hi));
                }
            }
        }
    }

    // ---- act constants for rows g*64 + u0 and g*64 + u0+1 ----
    float wih0[4][7], wih1[4][7], bias0[4], bias1[4];
#pragma unroll
    for (int g = 0; g < 4; ++g) {
        const int r0 = g * 64 + u0;
#pragma unroll
        for (int k = 0; k < 7; ++k) wih0[g][k] = eWih[r0 * INDIM + k];
        bias0[g] = ebih[r0] + ebhh[r0];
#pragma unroll
        for (int k = 0; k < 7; ++k) wih1[g][k] = eWih[(r0 + 1) * INDIM + k];
        bias1[g] = ebih[r0 + 1] + ebhh[r0 + 1];
    }

    // ---- init: step 0 reads parity buffer 1 ----
    lds_hhi[1][wid][lane] = 0;     lds_hlo[1][wid][lane] = 0;
    lds_hhi[1][wid + 4][lane] = 0; lds_hlo[1][wid + 4][lane] = 0;
    float c0 = 0.0f, c1 = 0.0f;    // c for (b_act, u0) and (b_act, u0+1)

    // ---- load x chunk 0 ----
    for (int i = tid; i < NBT * CHUNK * 8; i += 256) {
        int b = i >> 8;          // CHUNK*8 == 256 per batch
        int r = i & 255;
        int s = r >> 3;
        int k = r & 7;
        float v = 0.0f;
        if (k < 7) v = x[((size_t)(b0 + b) * SEQ + s) * INDIM + k];
        lds_x[0][s][b][k] = v;
    }
    __syncthreads();

    // ================= encoder: 512 serial steps, ONE barrier each =================
    for (int s = 0; s < SEQ; ++s) {
        const int cs  = s & (CHUNK - 1);
        const int buf = (s >> 5) & 1;
        const int rb  = (s & 1) ^ 1;   // h read-parity
        const int wb  = s & 1;         // h write-parity

        // ---- B fragments: b128 reads of pre-split bf16 h (cols = batches 0-7 x2) ----
        bf16x8 bhi[2], blo[2];
        {
            const int g16 = lane >> 4;
#pragma unroll
            for (int kt = 0; kt < 2; ++kt) {
                bhi[kt] = *(const bf16x8*)&lds_hhi[rb][b_act][kt * 32 + g16 * 8];
                blo[kt] = *(const bf16x8*)&lds_hlo[rb][b_act][kt * 32 + g16 * 8];
            }
        }

        // ---- MFMA: 3-pass hi/lo, 4 independent acc chains ----
        f32x4 acc[4] = {{0,0,0,0},{0,0,0,0},{0,0,0,0},{0,0,0,0}};
#pragma unroll
        for (int kt = 0; kt < 2; ++kt) {
#pragma unroll
            for (int g = 0; g < 4; ++g)
                acc[g] = __builtin_amdgcn_mfma_f32_16x16x32_bf16(a_hi[g][kt], bhi[kt], acc[g], 0, 0, 0);
#pragma unroll
            for (int g = 0; g < 4; ++g)
                acc[g] = __builtin_amdgcn_mfma_f32_16x16x32_bf16(a_lo[g][kt], bhi[kt], acc[g], 0, 0, 0);
#pragma unroll
            for (int g = 0; g < 4; ++g)
                acc[g] = __builtin_amdgcn_mfma_f32_16x16x32_bf16(a_hi[g][kt], blo[kt], acc[g], 0, 0, 0);
        }

        // ---- extract both r-slots (1 cndmask per gate per chain) ----
        float pre0[4], pre1[4];
#pragma unroll
        for (int g = 0; g < 4; ++g) {
            pre0[g] = q ? acc[g][2] : acc[g][0];
            pre1[g] = q ? acc[g][3] : acc[g][1];
        }

        // ---- two independent act chains per lane ----
        {
            f32x4 x0 = *(const f32x4*)&lds_x[buf][cs][b_act][0];
            f32x4 x1 = *(const f32x4*)&lds_x[buf][cs][b_act][4];
#pragma unroll
            for (int g = 0; g < 4; ++g) {
                float xd0 = x0[0] * wih0[g][0] + x0[1] * wih0[g][1] + x0[2] * wih0[g][2]
                          + x0[3] * wih0[g][3] + x1[0] * wih0[g][4] + x1[1] * wih0[g][5]
                          + x1[2] * wih0[g][6];
                float xd1 = x0[0] * wih1[g][0] + x0[1] * wih1[g][1] + x0[2] * wih1[g][2]
                          + x0[3] * wih1[g][3] + x1[0] * wih1[g][4] + x1[1] * wih1[g][5]
                          + x1[2] * wih1[g][6];
                pre0[g] += bias0[g] + xd0;
                pre1[g] += bias1[g] + xd1;
            }
            float ig0 = sigm(pre0[0]), fg0 = sigm(pre0[1]), gg0 = tanh_f(pre0[2]), og0 = sigm(pre0[3]);
            float ig1 = sigm(pre1[0]), fg1 = sigm(pre1[1]), gg1 = tanh_f(pre1[2]), og1 = sigm(pre1[3]);
            c0 = fg0 * c0 + ig0 * gg0;
            c1 = fg1 * c1 + ig1 * gg1;
            float h0 = og0 * tanh_f(c0);
            float h1 = og1 * tanh_f(c1);
            // truncation hi/lo split (exact residual by Sterbenz), packed writes
            union { float f; unsigned u; } h0u, h1u; h0u.f = h0; h1u.f = h1;
            union { unsigned u; float f; } t0, t1;
            t0.u = h0u.u & 0xffff0000u; t1.u = h1u.u & 0xffff0000u;
            union { float f; unsigned u; } r0u, r1u;
            r0u.f = h0 - t0.f; r1u.f = h1 - t1.f;
            unsigned packhi = (h0u.u >> 16) | (h1u.u & 0xffff0000u);
            unsigned packlo = (r0u.u >> 16) | (r1u.u & 0xffff0000u);
            *(unsigned*)&lds_hhi[wb][b_act][u0] = packhi;
            *(unsigned*)&lds_hlo[wb][b_act][u0] = packlo;
            if (s + 1 == SEQ) {
                lds_hf[b_act][u0] = h0;     lds_hf[b_act][u0 + 1] = h1;
                lds_cf[b_act][u0] = c0;     lds_cf[b_act][u0 + 1] = c1;
            }
        }

        // ---- prefetch next x chunk ----
        if (cs == 0 && s + CHUNK < SEQ) {
            const int nbuf = buf ^ 1;
            const int s0n  = s + CHUNK;
            for (int i = tid; i < NBT * CHUNK * 8; i += 256) {
                int b = i >> 8;
                int r = i & 255;
                int ss = r >> 3;
                int k = r & 7;
                float v = 0.0f;
                if (k < 7) v = x[((size_t)(b0 + b) * SEQ + (s0n + ss)) * INDIM + k];
                lds_x[nbuf][ss][b][k] = v;
            }
        }
        __syncthreads();   // h[wb] published for next step
    }
    // lds_hf/lds_cf hold h_enc/c_enc in (b, j) layout

    // ====== decoder gbase = b + h_enc @ dW_hh.T (fp32, one-time, 8 batches) ======
    {
        const int row = tid;   // 0..255
        float4 dwhh[16];
#pragma unroll
        for (int m4 = 0; m4 < 16; ++m4)
            dwhh[m4] = *reinterpret_cast<const float4*>(&dWhh[row * HDIM + m4 * 4]);
        const float dbias = dbih[row] + dbhh[row];

        float accd[NBT];
#pragma unroll
        for (int b = 0; b < NBT; ++b) accd[b] = dbias;
#pragma unroll
        for (int m4 = 0; m4 < 16; ++m4) {
            const float4 w = dwhh[m4];
            float4 hv[NBT];
#pragma unroll
            for (int b = 0; b < NBT; ++b)
                hv[b] = *reinterpret_cast<const float4*>(&lds_hf[b][m4 * 4]);
#pragma unroll
            for (int b = 0; b < NBT; ++b) accd[b] = fmaf(hv[b].x, w.x, accd[b]);
#pragma unroll
            for (int b = 0; b < NBT; ++b) accd[b] = fmaf(hv[b].y, w.y, accd[b]);
#pragma unroll
            for (int b = 0; b < NBT; ++b) accd[b] = fmaf(hv[b].z, w.z, accd[b]);
#pragma unroll
            for (int b = 0; b < NBT; ++b) accd[b] = fmaf(hv[b].w, w.w, accd[b]);
        }
#pragma unroll
        for (int b = 0; b < NBT; ++b) lds_g[b][row] = accd[b];
    }
    __syncthreads();

    // ================= decoder: wave = batch wid, then batch wid+4 =================
#pragma unroll
    for (int rep = 0; rep < 2; ++rep) {
        const int b = wid + rep * 4, j = lane;
        const float c_e = lds_cf[b][j];
        const float gb0 = lds_g[b][j];
        const float gb1 = lds_g[b][HDIM + j];
        const float gb2 = lds_g[b][2 * HDIM + j];
        const float gb3 = lds_g[b][3 * HDIM + j];

        const float w00 = dWih[(0 * HDIM + j) * QDIM + 0], w01 = dWih[(0 * HDIM + j) * QDIM + 1], w02 = dWih[(0 * HDIM + j) * QDIM + 2];
        const float w10 = dWih[(1 * HDIM + j) * QDIM + 0], w11 = dWih[(1 * HDIM + j) * QDIM + 1], w12 = dWih[(1 * HDIM + j) * QDIM + 2];
        const float w20 = dWih[(2 * HDIM + j) * QDIM + 0], w21 = dWih[(2 * HDIM + j) * QDIM + 1], w22 = dWih[(2 * HDIM + j) * QDIM + 2];
        const float w30 = dWih[(3 * HDIM + j) * QDIM + 0], w31 = dWih[(3 * HDIM + j) * QDIM + 1], w32 = dWih[(3 * HDIM + j) * QDIM + 2];
        const float ow0 = oW[0 * HDIM + j], ow1 = oW[1 * HDIM + j], ow2 = oW[2 * HDIM + j];
        const float ob0 = obv[0], ob1 = obv[1], ob2 = obv[2];

        float y0 = 0.0f, y1 = 0.0f, y2 = 0.0f;
        float* outp = out + (size_t)(b0 + b) * TDEC * QDIM;

        for (int t = 0; t < TDEC; ++t) {
            float g0 = gb0 + y0 * w00 + y1 * w01 + y2 * w02;
            float g1 = gb1 + y0 * w10 + y1 * w11 + y2 * w12;
            float g2 = gb2 + y0 * w20 + y1 * w21 + y2 * w22;
            float g3 = gb3 + y0 * w30 + y1 * w31 + y2 * w32;
            float ig = sigm(g0), fg = sigm(g1), gg = tanh_f(g2), og = sigm(g3);
            float c = fg * c_e + ig * gg;
            float h = og * tanh_f(c);
            float r0 = h * ow0, r1 = h * ow1, r2 = h * ow2;
#pragma unroll
            for (int d = 1; d < 64; d <<= 1) {
                r0 += __shfl_xor(r0, d);
                r1 += __shfl_xor(r1, d);
                r2 += __shfl_xor(r2, d);
            }
            y0 = r0 + ob0;
            y1 = r1 + ob1;
            y2 = r2 + ob2;
            if (j < QDIM) outp[t * QDIM + j] = (j == 0) ? y0 : (j == 1) ? y1 : y2;
        }
    }
}

extern "C" void kernel_launch(void* const* d_in, const int* in_sizes, int n_in,
                              void* d_out, int out_size, void* d_ws, size_t ws_size,
                              hipStream_t stream) {
    (void)in_sizes; (void)n_in; (void)d_ws; (void)ws_size; (void)out_size;
    const float* x    = (const float*)d_in[0];
    const float* eWih = (const float*)d_in[1];
    const float* eWhh = (const float*)d_in[2];
    const float* ebih = (const float*)d_in[3];
    const float* ebhh = (const float*)d_in[4];
    const float* dWih = (const float*)d_in[5];
    const float* dWhh = (const float*)d_in[6];
    const float* dbih = (const float*)d_in[7];
    const float* dbhh = (const float*)d_in[8];
    const float* oW   = (const float*)d_in[9];
    const float* obv  = (const float*)d_in[10];
    float* out = (float*)d_out;

    const int B = 2048;
    dim3 grid(B / NBT), block(256);
    enc_dec_kernel<<<grid, block, 0, stream>>>(x, eWih, eWhh, ebih, ebhh,
                                               dWih, dWhh, dbih, dbhh, oW, obv, out);
}

// Round 17
// 472.947 us; speedup vs baseline: 1.7199x; 1.2865x over previous
//
#include <hip/hip_runtime.h>

#define HDIM  64
#define INDIM 7
#define QDIM  3
#define TDEC  288
#define SEQ   512
#define NBT   8        // batches per block; 512-thread block; grid 256 = 1 block/CU, 2 waves/SIMD
#define CHUNK 32       // x timesteps staged per LDS chunk
#define HPAD  68       // fp32 h/c row stride (decoder handoff)
#define GPAD  264      // lds_g row stride (decoder gbase only)
#define HBST  80       // bf16 h row stride in shorts (160B)

typedef __attribute__((ext_vector_type(8))) short bf16x8;   // 8 bf16 in 4 VGPRs
typedef __attribute__((ext_vector_type(4))) float f32x4;

__device__ __forceinline__ float fast_rcp(float x) { return __builtin_amdgcn_rcpf(x); }
__device__ __forceinline__ float sigm(float x) { return fast_rcp(1.0f + __expf(-x)); }
__device__ __forceinline__ float tanh_f(float x) {
    float xx = fminf(fmaxf(x, -15.0f), 15.0f);
    float e = __expf(2.0f * xx);
    return (e - 1.0f) * fast_rcp(e + 1.0f);
}
// round-to-nearest-even fp32 -> bf16 bits (one-time paths)
__device__ __forceinline__ short f2bf(float f) {
    union { float f; unsigned u; } v; v.f = f;
    unsigned r = (v.u + 0x7fffu + ((v.u >> 16) & 1u)) >> 16;
    return (short)r;
}
__device__ __forceinline__ float bf2f(short s) {
    union { unsigned u; float f; } v; v.u = ((unsigned)(unsigned short)s) << 16;
    return v.f;
}

// R17: 8 batches/block, 512 threads (8 waves, 2/SIMD), grid 256 = 1 block/CU.
// ROW-PERMUTED A: tile t covers units 4t..4t+3; within-tile row = (u&3)*4 + g
// (unit-major, gate-minor). D layout (col=lane&15, row=(lane>>4)*4+reg) then
// gives lane L, reg r = gate r of (b = L&7, u = 4t + (L>>4)) -- the 4 gates
// land in the 4 acc regs directly. Wave w owns tiles {2w, 2w+1} = units
// [8w, 8w+8): 12 MFMA/wave/step (3-pass hi/lo retained), act = 1 chain/lane
// (tsel = (L>>3)&1 picks which tile's acc; 4 cndmasks), one barrier/step.
__global__ __launch_bounds__(512, 2)
void enc_dec_kernel(const float* __restrict__ x,
                    const float* __restrict__ eWih, const float* __restrict__ eWhh,
                    const float* __restrict__ ebih, const float* __restrict__ ebhh,
                    const float* __restrict__ dWih, const float* __restrict__ dWhh,
                    const float* __restrict__ dbih, const float* __restrict__ dbhh,
                    const float* __restrict__ oW,   const float* __restrict__ obv,
                    float* __restrict__ out)
{
    __shared__ __align__(16) short lds_hhi[2][NBT][HBST];    // h hi bf16, parity dbuf
    __shared__ __align__(16) short lds_hlo[2][NBT][HBST];    // h lo bf16
    __shared__ __align__(16) float lds_hf[NBT][HPAD];        // fp32 h_enc (final step)
    __shared__ __align__(16) float lds_cf[NBT][HPAD];        // fp32 c_enc (final step)
    __shared__ __align__(16) float lds_g[NBT][GPAD];         // decoder gbase staging
    __shared__ __align__(16) float lds_x[2][CHUNK][NBT][8];  // fp32 x, cs-major

    const int tid  = threadIdx.x;
    const int lane = tid & 63;
    const int wid  = tid >> 6;           // 0..7
    const int b0   = blockIdx.x * NBT;

    const int m    = lane & 15;          // A-row within tile / D col
    const int g16  = lane >> 4;          // k-subblock / D row-quad
    const int b_act = lane & 7;          // batch (cols 8..15 replicate 0..7)
    const int tsel  = (lane >> 3) & 1;   // which of the wave's 2 tiles this lane acts for
    const int u_act = wid * 8 + tsel * 4 + g16;   // unit this lane acts for

    // ---- A-fragments, row-permuted: tile tt (t = 2*wid+tt), row m -> unit
    // du = m>>2, gate g = m&3, global row = g*64 + 4*t + du ----
    bf16x8 a_hi[2][2], a_lo[2][2];
#pragma unroll
    for (int tt = 0; tt < 2; ++tt) {
        const int t = 2 * wid + tt;
        const int row = (m & 3) * 64 + 4 * t + (m >> 2);
#pragma unroll
        for (int kt = 0; kt < 2; ++kt) {
            const float* p = eWhh + (size_t)row * HDIM + kt * 32 + g16 * 8;
            f32x4 v0 = *(const f32x4*)p;
            f32x4 v1 = *(const f32x4*)(p + 4);
#pragma unroll
            for (int e = 0; e < 4; ++e) {
                short hi = f2bf(v0[e]);
                a_hi[tt][kt][e] = hi;
                a_lo[tt][kt][e] = f2bf(v0[e] - bf2f(hi));
            }
#pragma unroll
            for (int e = 0; e < 4; ++e) {
                short hi = f2bf(v1[e]);
                a_hi[tt][kt][4 + e] = hi;
                a_lo[tt][kt][4 + e] = f2bf(v1[e] - bf2f(hi));
            }
        }
    }

    // ---- act constants for rows g*64 + u_act ----
    float wih_r[4][7];
    float bias_r[4];
#pragma unroll
    for (int g = 0; g < 4; ++g) {
        const int r = g * 64 + u_act;
#pragma unroll
        for (int k = 0; k < 7; ++k) wih_r[g][k] = eWih[r * INDIM + k];
        bias_r[g] = ebih[r] + ebhh[r];
    }

    // ---- init: step 0 reads parity buffer 1 ----
    lds_hhi[1][wid][lane] = 0;
    lds_hlo[1][wid][lane] = 0;
    float c_reg = 0.0f;          // c for (b_act, u_act)

    // ---- load x chunk 0 (cs-major) ----
    for (int i = tid; i < NBT * CHUNK * 8; i += 512) {
        int b = i >> 8;          // CHUNK*8 == 256 per batch
        int r = i & 255;
        int s = r >> 3;
        int k = r & 7;
        float v = 0.0f;
        if (k < 7) v = x[((size_t)(b0 + b) * SEQ + s) * INDIM + k];
        lds_x[0][s][b][k] = v;
    }
    __syncthreads();

    // ================= encoder: 512 serial steps, ONE barrier each =================
    for (int s = 0; s < SEQ; ++s) {
        const int cs  = s & (CHUNK - 1);
        const int buf = (s >> 5) & 1;
        const int rb  = (s & 1) ^ 1;   // h read-parity
        const int wb  = s & 1;         // h write-parity

        // ---- B fragments: b128 reads of pre-split bf16 h (cols = batches 0-7 x2) ----
        bf16x8 bhi[2], blo[2];
#pragma unroll
        for (int kt = 0; kt < 2; ++kt) {
            bhi[kt] = *(const bf16x8*)&lds_hhi[rb][b_act][kt * 32 + g16 * 8];
            blo[kt] = *(const bf16x8*)&lds_hlo[rb][b_act][kt * 32 + g16 * 8];
        }

        // ---- MFMA: 2 tiles x (2 kt x 3-pass hi/lo) = 12, two independent chains ----
        f32x4 acc0 = {0, 0, 0, 0}, acc1 = {0, 0, 0, 0};
#pragma unroll
        for (int kt = 0; kt < 2; ++kt) {
            acc0 = __builtin_amdgcn_mfma_f32_16x16x32_bf16(a_hi[0][kt], bhi[kt], acc0, 0, 0, 0);
            acc1 = __builtin_amdgcn_mfma_f32_16x16x32_bf16(a_hi[1][kt], bhi[kt], acc1, 0, 0, 0);
            acc0 = __builtin_amdgcn_mfma_f32_16x16x32_bf16(a_lo[0][kt], bhi[kt], acc0, 0, 0, 0);
            acc1 = __builtin_amdgcn_mfma_f32_16x16x32_bf16(a_lo[1][kt], bhi[kt], acc1, 0, 0, 0);
            acc0 = __builtin_amdgcn_mfma_f32_16x16x32_bf16(a_hi[0][kt], blo[kt], acc0, 0, 0, 0);
            acc1 = __builtin_amdgcn_mfma_f32_16x16x32_bf16(a_hi[1][kt], blo[kt], acc1, 0, 0, 0);
        }

        // ---- gates are the regs of the selected tile (4 cndmasks) ----
        float pre[4];
#pragma unroll
        for (int g = 0; g < 4; ++g) pre[g] = tsel ? acc1[g] : acc0[g];

        // ---- activation: one chain per lane, (b_act, u_act) ----
        {
            f32x4 x0 = *(const f32x4*)&lds_x[buf][cs][b_act][0];
            f32x4 x1 = *(const f32x4*)&lds_x[buf][cs][b_act][4];
#pragma unroll
            for (int g = 0; g < 4; ++g) {
                pre[g] += bias_r[g]
                        + x0[0] * wih_r[g][0] + x0[1] * wih_r[g][1] + x0[2] * wih_r[g][2]
                        + x0[3] * wih_r[g][3] + x1[0] * wih_r[g][4] + x1[1] * wih_r[g][5]
                        + x1[2] * wih_r[g][6];
            }
            float ig = sigm(pre[0]), fg = sigm(pre[1]), gg = tanh_f(pre[2]), og = sigm(pre[3]);
            c_reg = fg * c_reg + ig * gg;
            float h = og * tanh_f(c_reg);
            // truncation hi/lo split: r = h - trunc16(h) exact (Sterbenz)
            union { float f; unsigned u; } hu; hu.f = h;
            unsigned hib = hu.u >> 16;
            union { unsigned u; float f; } ht; ht.u = hu.u & 0xffff0000u;
            union { float f; unsigned u; } ru; ru.f = h - ht.f;
            unsigned lob = ru.u >> 16;
            lds_hhi[wb][b_act][u_act] = (short)hib;
            lds_hlo[wb][b_act][u_act] = (short)lob;
            if (s + 1 == SEQ) {
                lds_hf[b_act][u_act] = h;
                lds_cf[b_act][u_act] = c_reg;
            }
        }

        // ---- prefetch next x chunk ----
        if (cs == 0 && s + CHUNK < SEQ) {
            const int nbuf = buf ^ 1;
            const int s0n  = s + CHUNK;
            for (int i = tid; i < NBT * CHUNK * 8; i += 512) {
                int b = i >> 8;
                int r = i & 255;
                int ss = r >> 3;
                int k = r & 7;
                float v = 0.0f;
                if (k < 7) v = x[((size_t)(b0 + b) * SEQ + (s0n + ss)) * INDIM + k];
                lds_x[nbuf][ss][b][k] = v;
            }
        }
        __syncthreads();   // h[wb] published for next step
    }
    // lds_hf/lds_cf hold h_enc/c_enc in (b, j) layout

    // ====== decoder gbase = b + h_enc @ dW_hh.T (fp32, one-time, 8 batches) ======
    {
        const int row = tid & 255;        // gate-matrix row
        const int gh  = tid >> 8;         // 0 -> batches 0-3, 1 -> batches 4-7
        float4 dwhh[16];
#pragma unroll
        for (int m4 = 0; m4 < 16; ++m4)
            dwhh[m4] = *reinterpret_cast<const float4*>(&dWhh[row * HDIM + m4 * 4]);
        const float dbias = dbih[row] + dbhh[row];

        float accd[4];
#pragma unroll
        for (int b = 0; b < 4; ++b) accd[b] = dbias;
#pragma unroll
        for (int m4 = 0; m4 < 16; ++m4) {
            const float4 w = dwhh[m4];
            float4 hv[4];
#pragma unroll
            for (int b = 0; b < 4; ++b)
                hv[b] = *reinterpret_cast<const float4*>(&lds_hf[gh * 4 + b][m4 * 4]);
#pragma unroll
            for (int b = 0; b < 4; ++b) accd[b] = fmaf(hv[b].x, w.x, accd[b]);
#pragma unroll
            for (int b = 0; b < 4; ++b) accd[b] = fmaf(hv[b].y, w.y, accd[b]);
#pragma unroll
            for (int b = 0; b < 4; ++b) accd[b] = fmaf(hv[b].z, w.z, accd[b]);
#pragma unroll
            for (int b = 0; b < 4; ++b) accd[b] = fmaf(hv[b].w, w.w, accd[b]);
        }
#pragma unroll
        for (int b = 0; b < 4; ++b) lds_g[gh * 4 + b][row] = accd[b];
    }
    __syncthreads();

    // ================= decoder: wave = one batch (8 waves, 8 batches) =================
    {
        const int b = wid, j = lane;
        const float c_e = lds_cf[b][j];
        const float gb0 = lds_g[b][j];
        const float gb1 = lds_g[b][HDIM + j];
        const float gb2 = lds_g[b][2 * HDIM + j];
        const float gb3 = lds_g[b][3 * HDIM + j];

        const float w00 = dWih[(0 * HDIM + j) * QDIM + 0], w01 = dWih[(0 * HDIM + j) * QDIM + 1], w02 = dWih[(0 * HDIM + j) * QDIM + 2];
        const float w10 = dWih[(1 * HDIM + j) * QDIM + 0], w11 = dWih[(1 * HDIM + j) * QDIM + 1], w12 = dWih[(1 * HDIM + j) * QDIM + 2];
        const float w20 = dWih[(2 * HDIM + j) * QDIM + 0], w21 = dWih[(2 * HDIM + j) * QDIM + 1], w22 = dWih[(2 * HDIM + j) * QDIM + 2];
        const float w30 = dWih[(3 * HDIM + j) * QDIM + 0], w31 = dWih[(3 * HDIM + j) * QDIM + 1], w32 = dWih[(3 * HDIM + j) * QDIM + 2];
        const float ow0 = oW[0 * HDIM + j], ow1 = oW[1 * HDIM + j], ow2 = oW[2 * HDIM + j];
        const float ob0 = obv[0], ob1 = obv[1], ob2 = obv[2];

        float y0 = 0.0f, y1 = 0.0f, y2 = 0.0f;
        float* outp = out + (size_t)(b0 + b) * TDEC * QDIM;

        for (int t = 0; t < TDEC; ++t) {
            float g0 = gb0 + y0 * w00 + y1 * w01 + y2 * w02;
            float g1 = gb1 + y0 * w10 + y1 * w11 + y2 * w12;
            float g2 = gb2 + y0 * w20 + y1 * w21 + y2 * w22;
            float g3 = gb3 + y0 * w30 + y1 * w31 + y2 * w32;
            float ig = sigm(g0), fg = sigm(g1), gg = tanh_f(g2), og = sigm(g3);
            float c = fg * c_e + ig * gg;
            float h = og * tanh_f(c);
            float r0 = h * ow0, r1 = h * ow1, r2 = h * ow2;
#pragma unroll
            for (int d = 1; d < 64; d <<= 1) {
                r0 += __shfl_xor(r0, d);
                r1 += __shfl_xor(r1, d);
                r2 += __shfl_xor(r2, d);
            }
            y0 = r0 + ob0;
            y1 = r1 + ob1;
            y2 = r2 + ob2;
            if (j < QDIM) outp[t * QDIM + j] = (j == 0) ? y0 : (j == 1) ? y1 : y2;
        }
    }
}

extern "C" void kernel_launch(void* const* d_in, const int* in_sizes, int n_in,
                              void* d_out, int out_size, void* d_ws, size_t ws_size,
                              hipStream_t stream) {
    (void)in_sizes; (void)n_in; (void)d_ws; (void)ws_size; (void)out_size;
    const float* x    = (const float*)d_in[0];
    const float* eWih = (const float*)d_in[1];
    const float* eWhh = (const float*)d_in[2];
    const float* ebih = (const float*)d_in[3];
    const float* ebhh = (const float*)d_in[4];
    const float* dWih = (const float*)d_in[5];
    const float* dWhh = (const float*)d_in[6];
    const float* dbih = (const float*)d_in[7];
    const float* dbhh = (const float*)d_in[8];
    const float* oW   = (const float*)d_in[9];
    const float* obv  = (const float*)d_in[10];
    float* out = (float*)d_out;

    const int B = 2048;
    dim3 grid(B / NBT), block(512);
    enc_dec_kernel<<<grid, block, 0, stream>>>(x, eWih, eWhh, ebih, ebhh,
                                               dWih, dWhh, dbih, dbhh, oW, obv, out);
}

// Round 18
// 443.671 us; speedup vs baseline: 1.8334x; 1.0660x over previous
//
#include <hip/hip_runtime.h>

#define HDIM  64
#define INDIM 7
#define QDIM  3
#define TDEC  288
#define SEQ   512
#define NBT   8        // batches per block; 512-thread block; grid 256 = 1 block/CU
#define CHUNK 32       // x timesteps staged per LDS chunk
#define HPAD  68       // fp32 h/c row stride (decoder handoff)
#define GPAD  264      // lds_g row stride (decoder gbase only)
#define HBST  80       // bf16 h row stride in shorts (160B)
#define PXU   264      // px floats per batch row (256 + pad -> b-stride 8 banks)

typedef __attribute__((ext_vector_type(8))) short bf16x8;   // 8 bf16 in 4 VGPRs
typedef __attribute__((ext_vector_type(4))) float f32x4;

__device__ __forceinline__ float fast_rcp(float x) { return __builtin_amdgcn_rcpf(x); }
__device__ __forceinline__ float sigm(float x) { return fast_rcp(1.0f + __expf(-x)); }
__device__ __forceinline__ float tanh_f(float x) {
    float xx = fminf(fmaxf(x, -15.0f), 15.0f);
    float e = __expf(2.0f * xx);
    return (e - 1.0f) * fast_rcp(e + 1.0f);
}
// round-to-nearest-even fp32 -> bf16 bits (one-time/amortized paths)
__device__ __forceinline__ short f2bf(float f) {
    union { float f; unsigned u; } v; v.f = f;
    unsigned r = (v.u + 0x7fffu + ((v.u >> 16) & 1u)) >> 16;
    return (short)r;
}
__device__ __forceinline__ float bf2f(short s) {
    union { unsigned u; float f; } v; v.u = ((unsigned)(unsigned short)s) << 16;
    return v.f;
}

// R18 = R17 (row-permuted A: gates land in acc regs; 12 main MFMA/wave/step;
// one barrier/step) + x@Wih+bias PRECOMPUTED via MFMA into lds_px in 4-step
// chunks (12 xW-MFMA/wave per chunk, amortized 3/step on the 16%-busy pipe).
// px layout [pxbuf][s&3][b][u*4+g] (gate-minor, written as one f32x4 per tile
// thanks to the same row permutation). Act: 1 b128 px read + 4 adds replaces
// 28 FMA + bias. K=8 xW GEMM: x slot 7 = 1.0 carries bias; 3-pass hi/lo.
__global__ __launch_bounds__(512, 2)
void enc_dec_kernel(const float* __restrict__ x,
                    const float* __restrict__ eWih, const float* __restrict__ eWhh,
                    const float* __restrict__ ebih, const float* __restrict__ ebhh,
                    const float* __restrict__ dWih, const float* __restrict__ dWhh,
                    const float* __restrict__ dbih, const float* __restrict__ dbhh,
                    const float* __restrict__ oW,   const float* __restrict__ obv,
                    float* __restrict__ out)
{
    __shared__ __align__(16) short lds_hhi[2][NBT][HBST];    // h hi bf16, parity dbuf
    __shared__ __align__(16) short lds_hlo[2][NBT][HBST];    // h lo bf16
    __shared__ __align__(16) short lds_xbh[2][CHUNK][NBT][8]; // x hi bf16 (k0..6, k7=1.0)
    __shared__ __align__(16) short lds_xbl[2][CHUNK][NBT][8]; // x lo bf16
    __shared__ __align__(16) short lds_xzero[8];             // zero stub (g16>0 reads)
    __shared__ __align__(16) float lds_px[2][4][NBT][PXU];   // pre_x, 4-step dbuf
    __shared__ __align__(16) float lds_hf[NBT][HPAD];        // fp32 h_enc (final step)
    __shared__ __align__(16) float lds_cf[NBT][HPAD];        // fp32 c_enc (final step)
    __shared__ __align__(16) float lds_g[NBT][GPAD];         // decoder gbase staging

    const int tid  = threadIdx.x;
    const int lane = tid & 63;
    const int wid  = tid >> 6;           // 0..7
    const int b0   = blockIdx.x * NBT;

    const int m    = lane & 15;          // A-row within tile / D col
    const int g16  = lane >> 4;          // k-subblock / D row-quad
    const int b_act = lane & 7;          // batch (cols 8..15 replicate 0..7)
    const int tsel  = (lane >> 3) & 1;   // which of the wave's 2 tiles this lane acts for
    const int u_act = wid * 8 + tsel * 4 + g16;   // unit this lane acts for

    // ---- main A-fragments, row-permuted: tile t=2*wid+tt, row m -> gate m&3,
    // unit 4t + (m>>2); hi/lo bf16, 3-pass ----
    bf16x8 a_hi[2][2], a_lo[2][2];
#pragma unroll
    for (int tt = 0; tt < 2; ++tt) {
        const int t = 2 * wid + tt;
        const int row = (m & 3) * 64 + 4 * t + (m >> 2);
#pragma unroll
        for (int kt = 0; kt < 2; ++kt) {
            const float* p = eWhh + (size_t)row * HDIM + kt * 32 + g16 * 8;
            f32x4 v0 = *(const f32x4*)p;
            f32x4 v1 = *(const f32x4*)(p + 4);
#pragma unroll
            for (int e = 0; e < 4; ++e) {
                short hi = f2bf(v0[e]);
                a_hi[tt][kt][e] = hi;
                a_lo[tt][kt][e] = f2bf(v0[e] - bf2f(hi));
            }
#pragma unroll
            for (int e = 0; e < 4; ++e) {
                short hi = f2bf(v1[e]);
                a_hi[tt][kt][4 + e] = hi;
                a_lo[tt][kt][4 + e] = f2bf(v1[e] - bf2f(hi));
            }
        }
    }

    // ---- xW A-fragments: same row permutation; K=8: e<7 Wih, e==7 bias ----
    bf16x8 axh[2], axl[2];
#pragma unroll
    for (int tt = 0; tt < 2; ++tt) {
        const int t = 2 * wid + tt;
        const int row = (m & 3) * 64 + 4 * t + (m >> 2);
        if (g16 == 0) {
#pragma unroll
            for (int e = 0; e < 8; ++e) {
                float v = (e < 7) ? eWih[row * INDIM + e] : (ebih[row] + ebhh[row]);
                short hi = f2bf(v);
                axh[tt][e] = hi;
                axl[tt][e] = f2bf(v - bf2f(hi));
            }
        } else {
#pragma unroll
            for (int e = 0; e < 8; ++e) { axh[tt][e] = 0; axl[tt][e] = 0; }
        }
    }

    // ---- init: step 0 reads h parity buffer 1; zero stub ----
    lds_hhi[1][wid][lane] = 0;
    lds_hlo[1][wid][lane] = 0;
    if (tid < 8) lds_xzero[tid] = 0;
    float c_reg = 0.0f;          // c for (b_act, u_act)

    // ---- x chunk loader (bf16 hi/lo RNE split; k==7 slot = 1.0) ----
    auto load_x_chunk = [&](int xbuf, int s0) {
        for (int i = tid; i < NBT * CHUNK * 8; i += 512) {
            int b = i >> 8;          // CHUNK*8 == 256 per batch
            int r = i & 255;
            int ss = r >> 3;
            int k = r & 7;
            float v = (k < 7) ? x[((size_t)(b0 + b) * SEQ + (s0 + ss)) * INDIM + k] : 1.0f;
            short hi = f2bf(v);
            lds_xbh[xbuf][ss][b][k] = hi;
            lds_xbl[xbuf][ss][b][k] = f2bf(v - bf2f(hi));
        }
    };

    // ---- xW GEMM for 4-step chunk j2 -> lds_px[j2&1] (needs x staged) ----
    auto compute_xw = [&](int j2) {
        const int sbase = 4 * j2;
        const int xbuf  = (sbase >> 5) & 1;
        const int sr0   = sbase & 31;
        const int col16 = lane & 15;
        const int pxb   = j2 & 1;
        bf16x8 bxh[2], bxl[2];
#pragma unroll
        for (int n = 0; n < 2; ++n) {
            const int srow = sr0 + 2 * n + (col16 >> 3);
            const short* ph = (g16 == 0) ? &lds_xbh[xbuf][srow][lane & 7][0] : &lds_xzero[0];
            const short* pl = (g16 == 0) ? &lds_xbl[xbuf][srow][lane & 7][0] : &lds_xzero[0];
            bxh[n] = *(const bf16x8*)ph;
            bxl[n] = *(const bf16x8*)pl;
        }
#pragma unroll
        for (int tt = 0; tt < 2; ++tt) {
#pragma unroll
            for (int n = 0; n < 2; ++n) {
                f32x4 p = {0, 0, 0, 0};
                p = __builtin_amdgcn_mfma_f32_16x16x32_bf16(axh[tt], bxh[n], p, 0, 0, 0);
                p = __builtin_amdgcn_mfma_f32_16x16x32_bf16(axl[tt], bxh[n], p, 0, 0, 0);
                p = __builtin_amdgcn_mfma_f32_16x16x32_bf16(axh[tt], bxl[n], p, 0, 0, 0);
                const int sl = 2 * n + (col16 >> 3);
                const int u  = 4 * (2 * wid + tt) + (lane >> 4);
                *(f32x4*)&lds_px[pxb][sl][lane & 7][u * 4] = p;
            }
        }
    };

    // ---- prologue: stage x chunk 0, compute px chunk 0 ----
    load_x_chunk(0, 0);
    __syncthreads();
    compute_xw(0);
    __syncthreads();

    // ================= encoder: 512 serial steps, ONE barrier each =================
    for (int s = 0; s < SEQ; ++s) {
        const int cs  = s & (CHUNK - 1);
        const int rb  = (s & 1) ^ 1;   // h read-parity
        const int wb  = s & 1;         // h write-parity

        // ---- B fragments: b128 reads of pre-split bf16 h (cols = batches 0-7 x2) ----
        bf16x8 bhi[2], blo[2];
#pragma unroll
        for (int kt = 0; kt < 2; ++kt) {
            bhi[kt] = *(const bf16x8*)&lds_hhi[rb][b_act][kt * 32 + g16 * 8];
            blo[kt] = *(const bf16x8*)&lds_hlo[rb][b_act][kt * 32 + g16 * 8];
        }

        // ---- main MFMA: 2 tiles x (2 kt x 3-pass) = 12, two independent chains ----
        f32x4 acc0 = {0, 0, 0, 0}, acc1 = {0, 0, 0, 0};
#pragma unroll
        for (int kt = 0; kt < 2; ++kt) {
            acc0 = __builtin_amdgcn_mfma_f32_16x16x32_bf16(a_hi[0][kt], bhi[kt], acc0, 0, 0, 0);
            acc1 = __builtin_amdgcn_mfma_f32_16x16x32_bf16(a_hi[1][kt], bhi[kt], acc1, 0, 0, 0);
            acc0 = __builtin_amdgcn_mfma_f32_16x16x32_bf16(a_lo[0][kt], bhi[kt], acc0, 0, 0, 0);
            acc1 = __builtin_amdgcn_mfma_f32_16x16x32_bf16(a_lo[1][kt], bhi[kt], acc1, 0, 0, 0);
            acc0 = __builtin_amdgcn_mfma_f32_16x16x32_bf16(a_hi[0][kt], blo[kt], acc0, 0, 0, 0);
            acc1 = __builtin_amdgcn_mfma_f32_16x16x32_bf16(a_hi[1][kt], blo[kt], acc1, 0, 0, 0);
        }

        // ---- gates are the regs of the selected tile (4 cndmasks) ----
        float pre[4];
#pragma unroll
        for (int g = 0; g < 4; ++g) pre[g] = tsel ? acc1[g] : acc0[g];

        // ---- xW for the NEXT 4-chunk (independent MFMAs; overlap with act) ----
        if ((s & 3) == 0 && s + 4 < SEQ) compute_xw((s >> 2) + 1);

        // ---- activation: one chain per lane, (b_act, u_act) ----
        {
            f32x4 px4 = *(const f32x4*)&lds_px[(s >> 2) & 1][s & 3][b_act][u_act * 4];
#pragma unroll
            for (int g = 0; g < 4; ++g) pre[g] += px4[g];
            float ig = sigm(pre[0]), fg = sigm(pre[1]), gg = tanh_f(pre[2]), og = sigm(pre[3]);
            c_reg = fg * c_reg + ig * gg;
            float h = og * tanh_f(c_reg);
            // truncation hi/lo split: r = h - trunc16(h) exact (Sterbenz)
            union { float f; unsigned u; } hu; hu.f = h;
            unsigned hib = hu.u >> 16;
            union { unsigned u; float f; } ht; ht.u = hu.u & 0xffff0000u;
            union { float f; unsigned u; } ru; ru.f = h - ht.f;
            unsigned lob = ru.u >> 16;
            lds_hhi[wb][b_act][u_act] = (short)hib;
            lds_hlo[wb][b_act][u_act] = (short)lob;
            if (s + 1 == SEQ) {
                lds_hf[b_act][u_act] = h;
                lds_cf[b_act][u_act] = c_reg;
            }
        }

        // ---- prefetch next x chunk ----
        if (cs == 0 && s + CHUNK < SEQ) {
            load_x_chunk(((s >> 5) & 1) ^ 1, s + CHUNK);
        }
        __syncthreads();   // h[wb] + px published for next step
    }
    // lds_hf/lds_cf hold h_enc/c_enc in (b, j) layout

    // ====== decoder gbase = b + h_enc @ dW_hh.T (fp32, one-time, 8 batches) ======
    {
        const int row = tid & 255;        // gate-matrix row
        const int gh  = tid >> 8;         // 0 -> batches 0-3, 1 -> batches 4-7
        float4 dwhh[16];
#pragma unroll
        for (int m4 = 0; m4 < 16; ++m4)
            dwhh[m4] = *reinterpret_cast<const float4*>(&dWhh[row * HDIM + m4 * 4]);
        const float dbias = dbih[row] + dbhh[row];

        float accd[4];
#pragma unroll
        for (int b = 0; b < 4; ++b) accd[b] = dbias;
#pragma unroll
        for (int m4 = 0; m4 < 16; ++m4) {
            const float4 w = dwhh[m4];
            float4 hv[4];
#pragma unroll
            for (int b = 0; b < 4; ++b)
                hv[b] = *reinterpret_cast<const float4*>(&lds_hf[gh * 4 + b][m4 * 4]);
#pragma unroll
            for (int b = 0; b < 4; ++b) accd[b] = fmaf(hv[b].x, w.x, accd[b]);
#pragma unroll
            for (int b = 0; b < 4; ++b) accd[b] = fmaf(hv[b].y, w.y, accd[b]);
#pragma unroll
            for (int b = 0; b < 4; ++b) accd[b] = fmaf(hv[b].z, w.z, accd[b]);
#pragma unroll
            for (int b = 0; b < 4; ++b) accd[b] = fmaf(hv[b].w, w.w, accd[b]);
        }
#pragma unroll
        for (int b = 0; b < 4; ++b) lds_g[gh * 4 + b][row] = accd[b];
    }
    __syncthreads();

    // ================= decoder: wave = one batch (8 waves, 8 batches) =================
    {
        const int b = wid, j = lane;
        const float c_e = lds_cf[b][j];
        const float gb0 = lds_g[b][j];
        const float gb1 = lds_g[b][HDIM + j];
        const float gb2 = lds_g[b][2 * HDIM + j];
        const float gb3 = lds_g[b][3 * HDIM + j];

        const float w00 = dWih[(0 * HDIM + j) * QDIM + 0], w01 = dWih[(0 * HDIM + j) * QDIM + 1], w02 = dWih[(0 * HDIM + j) * QDIM + 2];
        const float w10 = dWih[(1 * HDIM + j) * QDIM + 0], w11 = dWih[(1 * HDIM + j) * QDIM + 1], w12 = dWih[(1 * HDIM + j) * QDIM + 2];
        const float w20 = dWih[(2 * HDIM + j) * QDIM + 0], w21 = dWih[(2 * HDIM + j) * QDIM + 1], w22 = dWih[(2 * HDIM + j) * QDIM + 2];
        const float w30 = dWih[(3 * HDIM + j) * QDIM + 0], w31 = dWih[(3 * HDIM + j) * QDIM + 1], w32 = dWih[(3 * HDIM + j) * QDIM + 2];
        const float ow0 = oW[0 * HDIM + j], ow1 = oW[1 * HDIM + j], ow2 = oW[2 * HDIM + j];
        const float ob0 = obv[0], ob1 = obv[1], ob2 = obv[2];

        float y0 = 0.0f, y1 = 0.0f, y2 = 0.0f;
        float* outp = out + (size_t)(b0 + b) * TDEC * QDIM;

        for (int t = 0; t < TDEC; ++t) {
            float g0 = gb0 + y0 * w00 + y1 * w01 + y2 * w02;
            float g1 = gb1 + y0 * w10 + y1 * w11 + y2 * w12;
            float g2 = gb2 + y0 * w20 + y1 * w21 + y2 * w22;
            float g3 = gb3 + y0 * w30 + y1 * w31 + y2 * w32;
            float ig = sigm(g0), fg = sigm(g1), gg = tanh_f(g2), og = sigm(g3);
            float c = fg * c_e + ig * gg;
            float h = og * tanh_f(c);
            float r0 = h * ow0, r1 = h * ow1, r2 = h * ow2;
#pragma unroll
            for (int d = 1; d < 64; d <<= 1) {
                r0 += __shfl_xor(r0, d);
                r1 += __shfl_xor(r1, d);
                r2 += __shfl_xor(r2, d);
            }
            y0 = r0 + ob0;
            y1 = r1 + ob1;
            y2 = r2 + ob2;
            if (j < QDIM) outp[t * QDIM + j] = (j == 0) ? y0 : (j == 1) ? y1 : y2;
        }
    }
}

extern "C" void kernel_launch(void* const* d_in, const int* in_sizes, int n_in,
                              void* d_out, int out_size, void* d_ws, size_t ws_size,
                              hipStream_t stream) {
    (void)in_sizes; (void)n_in; (void)d_ws; (void)ws_size; (void)out_size;
    const float* x    = (const float*)d_in[0];
    const float* eWih = (const float*)d_in[1];
    const float* eWhh = (const float*)d_in[2];
    const float* ebih = (const float*)d_in[3];
    const float* ebhh = (const float*)d_in[4];
    const float* dWih = (const float*)d_in[5];
    const float* dWhh = (const float*)d_in[6];
    const float* dbih = (const float*)d_in[7];
    const float* dbhh = (const float*)d_in[8];
    const float* oW   = (const float*)d_in[9];
    const float* obv  = (const float*)d_in[10];
    float* out = (float*)d_out;

    const int B = 2048;
    dim3 grid(B / NBT), block(512);
    enc_dec_kernel<<<grid, block, 0, stream>>>(x, eWih, eWhh, ebih, ebhh,
                                               dWih, dWhh, dbih, dbhh, oW, obv, out);
}

// Round 19
// 434.416 us; speedup vs baseline: 1.8725x; 1.0213x over previous
//
#include <hip/hip_runtime.h>

#define HDIM  64
#define INDIM 7
#define QDIM  3
#define TDEC  288
#define SEQ   512
#define NBT   8        // batches per block; 512-thread block; grid 256 = 1 block/CU
#define CHUNK 32       // x timesteps staged per LDS chunk
#define HPAD  68       // fp32 h/c row stride (decoder handoff)
#define GPAD  264      // lds_g row stride (decoder gbase only)
#define HBST  80       // bf16 h row stride in shorts (160B)
#define PXU   264      // px floats per batch row

typedef __attribute__((ext_vector_type(8))) short bf16x8;   // 8 bf16 in 4 VGPRs
typedef __attribute__((ext_vector_type(4))) float f32x4;

__device__ __forceinline__ float fast_rcp(float x) { return __builtin_amdgcn_rcpf(x); }
__device__ __forceinline__ float sigm(float x) { return fast_rcp(1.0f + __expf(-x)); }
__device__ __forceinline__ float tanh_f(float x) {
    float xx = fminf(fmaxf(x, -15.0f), 15.0f);
    float e = __expf(2.0f * xx);
    return (e - 1.0f) * fast_rcp(e + 1.0f);
}
// round-to-nearest-even fp32 -> bf16 bits (one-time/amortized paths)
__device__ __forceinline__ short f2bf(float f) {
    union { float f; unsigned u; } v; v.f = f;
    unsigned r = (v.u + 0x7fffu + ((v.u >> 16) & 1u)) >> 16;
    return (short)r;
}
__device__ __forceinline__ float bf2f(short s) {
    union { unsigned u; float f; } v; v.u = ((unsigned)(unsigned short)s) << 16;
    return v.f;
}

// R19 = R18 (row-permuted A; xW+bias precomputed via MFMA into px) with two
// ISSUE-ORDER fixes (zero math change):
//  (a) px read hoisted to the TOP of the step -> its ~120cyc LDS latency
//      hides under the B-frag reads + 12 main MFMAs (was issued right
//      before use in act = fully exposed every step).
//  (b) compute_xw moved AFTER the h-publish -> the xW x-read wait + 12 MFMA
//      issue no longer stall act's issue every 4th step (act depends only on
//      pre + previous chunk's px; double-buffer disjointness unchanged).
__global__ __launch_bounds__(512, 2)
void enc_dec_kernel(const float* __restrict__ x,
                    const float* __restrict__ eWih, const float* __restrict__ eWhh,
                    const float* __restrict__ ebih, const float* __restrict__ ebhh,
                    const float* __restrict__ dWih, const float* __restrict__ dWhh,
                    const float* __restrict__ dbih, const float* __restrict__ dbhh,
                    const float* __restrict__ oW,   const float* __restrict__ obv,
                    float* __restrict__ out)
{
    __shared__ __align__(16) short lds_hhi[2][NBT][HBST];    // h hi bf16, parity dbuf
    __shared__ __align__(16) short lds_hlo[2][NBT][HBST];    // h lo bf16
    __shared__ __align__(16) short lds_xbh[2][CHUNK][NBT][8]; // x hi bf16 (k0..6, k7=1.0)
    __shared__ __align__(16) short lds_xbl[2][CHUNK][NBT][8]; // x lo bf16
    __shared__ __align__(16) short lds_xzero[8];             // zero stub (g16>0 reads)
    __shared__ __align__(16) float lds_px[2][4][NBT][PXU];   // pre_x, 4-step dbuf
    __shared__ __align__(16) float lds_hf[NBT][HPAD];        // fp32 h_enc (final step)
    __shared__ __align__(16) float lds_cf[NBT][HPAD];        // fp32 c_enc (final step)
    __shared__ __align__(16) float lds_g[NBT][GPAD];         // decoder gbase staging

    const int tid  = threadIdx.x;
    const int lane = tid & 63;
    const int wid  = tid >> 6;           // 0..7
    const int b0   = blockIdx.x * NBT;

    const int m    = lane & 15;          // A-row within tile / D col
    const int g16  = lane >> 4;          // k-subblock / D row-quad
    const int b_act = lane & 7;          // batch (cols 8..15 replicate 0..7)
    const int tsel  = (lane >> 3) & 1;   // which of the wave's 2 tiles this lane acts for
    const int u_act = wid * 8 + tsel * 4 + g16;   // unit this lane acts for

    // ---- main A-fragments, row-permuted: tile t=2*wid+tt, row m -> gate m&3,
    // unit 4t + (m>>2); hi/lo bf16, 3-pass ----
    bf16x8 a_hi[2][2], a_lo[2][2];
#pragma unroll
    for (int tt = 0; tt < 2; ++tt) {
        const int t = 2 * wid + tt;
        const int row = (m & 3) * 64 + 4 * t + (m >> 2);
#pragma unroll
        for (int kt = 0; kt < 2; ++kt) {
            const float* p = eWhh + (size_t)row * HDIM + kt * 32 + g16 * 8;
            f32x4 v0 = *(const f32x4*)p;
            f32x4 v1 = *(const f32x4*)(p + 4);
#pragma unroll
            for (int e = 0; e < 4; ++e) {
                short hi = f2bf(v0[e]);
                a_hi[tt][kt][e] = hi;
                a_lo[tt][kt][e] = f2bf(v0[e] - bf2f(hi));
            }
#pragma unroll
            for (int e = 0; e < 4; ++e) {
                short hi = f2bf(v1[e]);
                a_hi[tt][kt][4 + e] = hi;
                a_lo[tt][kt][4 + e] = f2bf(v1[e] - bf2f(hi));
            }
        }
    }

    // ---- xW A-fragments: same row permutation; K=8: e<7 Wih, e==7 bias ----
    bf16x8 axh[2], axl[2];
#pragma unroll
    for (int tt = 0; tt < 2; ++tt) {
        const int t = 2 * wid + tt;
        const int row = (m & 3) * 64 + 4 * t + (m >> 2);
        if (g16 == 0) {
#pragma unroll
            for (int e = 0; e < 8; ++e) {
                float v = (e < 7) ? eWih[row * INDIM + e] : (ebih[row] + ebhh[row]);
                short hi = f2bf(v);
                axh[tt][e] = hi;
                axl[tt][e] = f2bf(v - bf2f(hi));
            }
        } else {
#pragma unroll
            for (int e = 0; e < 8; ++e) { axh[tt][e] = 0; axl[tt][e] = 0; }
        }
    }

    // ---- init: step 0 reads h parity buffer 1; zero stub ----
    lds_hhi[1][wid][lane] = 0;
    lds_hlo[1][wid][lane] = 0;
    if (tid < 8) lds_xzero[tid] = 0;
    float c_reg = 0.0f;          // c for (b_act, u_act)

    // ---- x chunk loader (bf16 hi/lo RNE split; k==7 slot = 1.0) ----
    auto load_x_chunk = [&](int xbuf, int s0) {
        for (int i = tid; i < NBT * CHUNK * 8; i += 512) {
            int b = i >> 8;          // CHUNK*8 == 256 per batch
            int r = i & 255;
            int ss = r >> 3;
            int k = r & 7;
            float v = (k < 7) ? x[((size_t)(b0 + b) * SEQ + (s0 + ss)) * INDIM + k] : 1.0f;
            short hi = f2bf(v);
            lds_xbh[xbuf][ss][b][k] = hi;
            lds_xbl[xbuf][ss][b][k] = f2bf(v - bf2f(hi));
        }
    };

    // ---- xW GEMM for 4-step chunk j2 -> lds_px[j2&1] (needs x staged) ----
    auto compute_xw = [&](int j2) {
        const int sbase = 4 * j2;
        const int xbuf  = (sbase >> 5) & 1;
        const int sr0   = sbase & 31;
        const int col16 = lane & 15;
        const int pxb   = j2 & 1;
        bf16x8 bxh[2], bxl[2];
#pragma unroll
        for (int n = 0; n < 2; ++n) {
            const int srow = sr0 + 2 * n + (col16 >> 3);
            const short* ph = (g16 == 0) ? &lds_xbh[xbuf][srow][lane & 7][0] : &lds_xzero[0];
            const short* pl = (g16 == 0) ? &lds_xbl[xbuf][srow][lane & 7][0] : &lds_xzero[0];
            bxh[n] = *(const bf16x8*)ph;
            bxl[n] = *(const bf16x8*)pl;
        }
#pragma unroll
        for (int tt = 0; tt < 2; ++tt) {
#pragma unroll
            for (int n = 0; n < 2; ++n) {
                f32x4 p = {0, 0, 0, 0};
                p = __builtin_amdgcn_mfma_f32_16x16x32_bf16(axh[tt], bxh[n], p, 0, 0, 0);
                p = __builtin_amdgcn_mfma_f32_16x16x32_bf16(axl[tt], bxh[n], p, 0, 0, 0);
                p = __builtin_amdgcn_mfma_f32_16x16x32_bf16(axh[tt], bxl[n], p, 0, 0, 0);
                const int sl = 2 * n + (col16 >> 3);
                const int u  = 4 * (2 * wid + tt) + (lane >> 4);
                *(f32x4*)&lds_px[pxb][sl][lane & 7][u * 4] = p;
            }
        }
    };

    // ---- prologue: stage x chunk 0, compute px chunk 0 ----
    load_x_chunk(0, 0);
    __syncthreads();
    compute_xw(0);
    __syncthreads();

    // ================= encoder: 512 serial steps, ONE barrier each =================
    for (int s = 0; s < SEQ; ++s) {
        const int cs  = s & (CHUNK - 1);
        const int rb  = (s & 1) ^ 1;   // h read-parity
        const int wb  = s & 1;         // h write-parity

        // ---- (a) px prefetch for THIS step: issue first, use last ----
        f32x4 px4 = *(const f32x4*)&lds_px[(s >> 2) & 1][s & 3][b_act][u_act * 4];

        // ---- B fragments: b128 reads of pre-split bf16 h (cols = batches 0-7 x2) ----
        bf16x8 bhi[2], blo[2];
#pragma unroll
        for (int kt = 0; kt < 2; ++kt) {
            bhi[kt] = *(const bf16x8*)&lds_hhi[rb][b_act][kt * 32 + g16 * 8];
            blo[kt] = *(const bf16x8*)&lds_hlo[rb][b_act][kt * 32 + g16 * 8];
        }

        // ---- main MFMA: 2 tiles x (2 kt x 3-pass) = 12, two independent chains ----
        f32x4 acc0 = {0, 0, 0, 0}, acc1 = {0, 0, 0, 0};
#pragma unroll
        for (int kt = 0; kt < 2; ++kt) {
            acc0 = __builtin_amdgcn_mfma_f32_16x16x32_bf16(a_hi[0][kt], bhi[kt], acc0, 0, 0, 0);
            acc1 = __builtin_amdgcn_mfma_f32_16x16x32_bf16(a_hi[1][kt], bhi[kt], acc1, 0, 0, 0);
            acc0 = __builtin_amdgcn_mfma_f32_16x16x32_bf16(a_lo[0][kt], bhi[kt], acc0, 0, 0, 0);
            acc1 = __builtin_amdgcn_mfma_f32_16x16x32_bf16(a_lo[1][kt], bhi[kt], acc1, 0, 0, 0);
            acc0 = __builtin_amdgcn_mfma_f32_16x16x32_bf16(a_hi[0][kt], blo[kt], acc0, 0, 0, 0);
            acc1 = __builtin_amdgcn_mfma_f32_16x16x32_bf16(a_hi[1][kt], blo[kt], acc1, 0, 0, 0);
        }

        // ---- gates are the regs of the selected tile (4 cndmasks) ----
        float pre[4];
#pragma unroll
        for (int g = 0; g < 4; ++g) pre[g] = tsel ? acc1[g] : acc0[g];

        // ---- activation: one chain per lane, (b_act, u_act) ----
        {
#pragma unroll
            for (int g = 0; g < 4; ++g) pre[g] += px4[g];
            float ig = sigm(pre[0]), fg = sigm(pre[1]), gg = tanh_f(pre[2]), og = sigm(pre[3]);
            c_reg = fg * c_reg + ig * gg;
            float h = og * tanh_f(c_reg);
            // truncation hi/lo split: r = h - trunc16(h) exact (Sterbenz)
            union { float f; unsigned u; } hu; hu.f = h;
            unsigned hib = hu.u >> 16;
            union { unsigned u; float f; } ht; ht.u = hu.u & 0xffff0000u;
            union { float f; unsigned u; } ru; ru.f = h - ht.f;
            unsigned lob = ru.u >> 16;
            lds_hhi[wb][b_act][u_act] = (short)hib;
            lds_hlo[wb][b_act][u_act] = (short)lob;
            if (s + 1 == SEQ) {
                lds_hf[b_act][u_act] = h;
                lds_cf[b_act][u_act] = c_reg;
            }
        }

        // ---- (b) xW for the NEXT 4-chunk: off act's issue path now ----
        if ((s & 3) == 0 && s + 4 < SEQ) compute_xw((s >> 2) + 1);

        // ---- prefetch next x chunk ----
        if (cs == 0 && s + CHUNK < SEQ) {
            load_x_chunk(((s >> 5) & 1) ^ 1, s + CHUNK);
        }
        __syncthreads();   // h[wb] + px published for next step
    }
    // lds_hf/lds_cf hold h_enc/c_enc in (b, j) layout

    // ====== decoder gbase = b + h_enc @ dW_hh.T (fp32, one-time, 8 batches) ======
    {
        const int row = tid & 255;        // gate-matrix row
        const int gh  = tid >> 8;         // 0 -> batches 0-3, 1 -> batches 4-7
        float4 dwhh[16];
#pragma unroll
        for (int m4 = 0; m4 < 16; ++m4)
            dwhh[m4] = *reinterpret_cast<const float4*>(&dWhh[row * HDIM + m4 * 4]);
        const float dbias = dbih[row] + dbhh[row];

        float accd[4];
#pragma unroll
        for (int b = 0; b < 4; ++b) accd[b] = dbias;
#pragma unroll
        for (int m4 = 0; m4 < 16; ++m4) {
            const float4 w = dwhh[m4];
            float4 hv[4];
#pragma unroll
            for (int b = 0; b < 4; ++b)
                hv[b] = *reinterpret_cast<const float4*>(&lds_hf[gh * 4 + b][m4 * 4]);
#pragma unroll
            for (int b = 0; b < 4; ++b) accd[b] = fmaf(hv[b].x, w.x, accd[b]);
#pragma unroll
            for (int b = 0; b < 4; ++b) accd[b] = fmaf(hv[b].y, w.y, accd[b]);
#pragma unroll
            for (int b = 0; b < 4; ++b) accd[b] = fmaf(hv[b].z, w.z, accd[b]);
#pragma unroll
            for (int b = 0; b < 4; ++b) accd[b] = fmaf(hv[b].w, w.w, accd[b]);
        }
#pragma unroll
        for (int b = 0; b < 4; ++b) lds_g[gh * 4 + b][row] = accd[b];
    }
    __syncthreads();

    // ================= decoder: wave = one batch (8 waves, 8 batches) =================
    {
        const int b = wid, j = lane;
        const float c_e = lds_cf[b][j];
        const float gb0 = lds_g[b][j];
        const float gb1 = lds_g[b][HDIM + j];
        const float gb2 = lds_g[b][2 * HDIM + j];
        const float gb3 = lds_g[b][3 * HDIM + j];

        const float w00 = dWih[(0 * HDIM + j) * QDIM + 0], w01 = dWih[(0 * HDIM + j) * QDIM + 1], w02 = dWih[(0 * HDIM + j) * QDIM + 2];
        const float w10 = dWih[(1 * HDIM + j) * QDIM + 0], w11 = dWih[(1 * HDIM + j) * QDIM + 1], w12 = dWih[(1 * HDIM + j) * QDIM + 2];
        const float w20 = dWih[(2 * HDIM + j) * QDIM + 0], w21 = dWih[(2 * HDIM + j) * QDIM + 1], w22 = dWih[(2 * HDIM + j) * QDIM + 2];
        const float w30 = dWih[(3 * HDIM + j) * QDIM + 0], w31 = dWih[(3 * HDIM + j) * QDIM + 1], w32 = dWih[(3 * HDIM + j) * QDIM + 2];
        const float ow0 = oW[0 * HDIM + j], ow1 = oW[1 * HDIM + j], ow2 = oW[2 * HDIM + j];
        const float ob0 = obv[0], ob1 = obv[1], ob2 = obv[2];

        float y0 = 0.0f, y1 = 0.0f, y2 = 0.0f;
        float* outp = out + (size_t)(b0 + b) * TDEC * QDIM;

        for (int t = 0; t < TDEC; ++t) {
            float g0 = gb0 + y0 * w00 + y1 * w01 + y2 * w02;
            float g1 = gb1 + y0 * w10 + y1 * w11 + y2 * w12;
            float g2 = gb2 + y0 * w20 + y1 * w21 + y2 * w22;
            float g3 = gb3 + y0 * w30 + y1 * w31 + y2 * w32;
            float ig = sigm(g0), fg = sigm(g1), gg = tanh_f(g2), og = sigm(g3);
            float c = fg * c_e + ig * gg;
            float h = og * tanh_f(c);
            float r0 = h * ow0, r1 = h * ow1, r2 = h * ow2;
#pragma unroll
            for (int d = 1; d < 64; d <<= 1) {
                r0 += __shfl_xor(r0, d);
                r1 += __shfl_xor(r1, d);
                r2 += __shfl_xor(r2, d);
            }
            y0 = r0 + ob0;
            y1 = r1 + ob1;
            y2 = r2 + ob2;
            if (j < QDIM) outp[t * QDIM + j] = (j == 0) ? y0 : (j == 1) ? y1 : y2;
        }
    }
}

extern "C" void kernel_launch(void* const* d_in, const int* in_sizes, int n_in,
                              void* d_out, int out_size, void* d_ws, size_t ws_size,
                              hipStream_t stream) {
    (void)in_sizes; (void)n_in; (void)d_ws; (void)ws_size; (void)out_size;
    const float* x    = (const float*)d_in[0];
    const float* eWih = (const float*)d_in[1];
    const float* eWhh = (const float*)d_in[2];
    const float* ebih = (const float*)d_in[3];
    const float* ebhh = (const float*)d_in[4];
    const float* dWih = (const float*)d_in[5];
    const float* dWhh = (const float*)d_in[6];
    const float* dbih = (const float*)d_in[7];
    const float* dbhh = (const float*)d_in[8];
    const float* oW   = (const float*)d_in[9];
    const float* obv  = (const float*)d_in[10];
    float* out = (float*)d_out;

    const int B = 2048;
    dim3 grid(B / NBT), block(512);
    enc_dec_kernel<<<grid, block, 0, stream>>>(x, eWih, eWhh, ebih, ebhh,
                                               dWih, dWhh, dbih, dbhh, oW, obv, out);
}

// Round 20
// 405.044 us; speedup vs baseline: 2.0082x; 1.0725x over previous
//
#include <hip/hip_runtime.h>

#define HDIM  64
#define INDIM 7
#define QDIM  3
#define TDEC  288
#define SEQ   512
#define NBT   8        // batches per block; 512-thread block; grid 256 = 1 block/CU
#define CHUNK 32       // x timesteps staged per LDS chunk
#define HPAD  68       // fp32 h/c row stride (decoder handoff)
#define GPAD  264      // lds_g row stride (decoder gbase only)
#define HBST  80       // bf16 h row stride in shorts (160B)
#define PXU   264      // px floats per batch row

typedef __attribute__((ext_vector_type(8))) short bf16x8;   // 8 bf16 in 4 VGPRs
typedef __attribute__((ext_vector_type(4))) float f32x4;

__device__ __forceinline__ float fast_rcp(float x) { return __builtin_amdgcn_rcpf(x); }
__device__ __forceinline__ float sigm(float x) { return fast_rcp(1.0f + __expf(-x)); }
// 5-op inf-safe tanh: 1 - 2/(1+e^{2x});  x->+inf: exp->inf, rcp->0 -> 1;
// x->-inf: exp->0, rcp(1)=1 -> -1. No clamp needed.
__device__ __forceinline__ float tanh_f(float x) {
    float e = __expf(2.0f * x);
    return fmaf(-2.0f, fast_rcp(1.0f + e), 1.0f);
}
// round-to-nearest-even fp32 -> bf16 bits
__device__ __forceinline__ short f2bf(float f) {
    union { float f; unsigned u; } v; v.f = f;
    unsigned r = (v.u + 0x7fffu + ((v.u >> 16) & 1u)) >> 16;
    return (short)r;
}
__device__ __forceinline__ float bf2f(short s) {
    union { unsigned u; float f; } v; v.u = ((unsigned)(unsigned short)s) << 16;
    return v.f;
}

// R20 = R19 (row-permuted A; xW+bias via MFMA into px; issue-order fixes)
//  + h stored as SINGLE RNE bf16 (h-lo plane dropped): B-frag LDS traffic
//    halves (2 b128/lane/step), MFMA 12->8/wave/step, act tail loses the
//    hi/lo split. W stays hi/lo (2-pass: Whi*h + Wlo*h). Predicted absmax
//    ~1-2e-3 (threshold 3.24e-3); revert to R19 if exceeded.
//  + 5-op clamp-free tanh (shorter dependent act chain).
__global__ __launch_bounds__(512, 2)
void enc_dec_kernel(const float* __restrict__ x,
                    const float* __restrict__ eWih, const float* __restrict__ eWhh,
                    const float* __restrict__ ebih, const float* __restrict__ ebhh,
                    const float* __restrict__ dWih, const float* __restrict__ dWhh,
                    const float* __restrict__ dbih, const float* __restrict__ dbhh,
                    const float* __restrict__ oW,   const float* __restrict__ obv,
                    float* __restrict__ out)
{
    __shared__ __align__(16) short lds_hh[2][NBT][HBST];     // h bf16 (RNE), parity dbuf
    __shared__ __align__(16) short lds_xbh[2][CHUNK][NBT][8]; // x hi bf16 (k0..6, k7=1.0)
    __shared__ __align__(16) short lds_xbl[2][CHUNK][NBT][8]; // x lo bf16
    __shared__ __align__(16) short lds_xzero[8];             // zero stub (g16>0 reads)
    __shared__ __align__(16) float lds_px[2][4][NBT][PXU];   // pre_x, 4-step dbuf
    __shared__ __align__(16) float lds_hf[NBT][HPAD];        // fp32 h_enc (final step)
    __shared__ __align__(16) float lds_cf[NBT][HPAD];        // fp32 c_enc (final step)
    __shared__ __align__(16) float lds_g[NBT][GPAD];         // decoder gbase staging

    const int tid  = threadIdx.x;
    const int lane = tid & 63;
    const int wid  = tid >> 6;           // 0..7
    const int b0   = blockIdx.x * NBT;

    const int m    = lane & 15;          // A-row within tile / D col
    const int g16  = lane >> 4;          // k-subblock / D row-quad
    const int b_act = lane & 7;          // batch (cols 8..15 replicate 0..7)
    const int tsel  = (lane >> 3) & 1;   // which of the wave's 2 tiles this lane acts for
    const int u_act = wid * 8 + tsel * 4 + g16;   // unit this lane acts for

    // ---- main A-fragments, row-permuted: tile t=2*wid+tt, row m -> gate m&3,
    // unit 4t + (m>>2); W hi/lo bf16 (2-pass vs single-bf16 h) ----
    bf16x8 a_hi[2][2], a_lo[2][2];
#pragma unroll
    for (int tt = 0; tt < 2; ++tt) {
        const int t = 2 * wid + tt;
        const int row = (m & 3) * 64 + 4 * t + (m >> 2);
#pragma unroll
        for (int kt = 0; kt < 2; ++kt) {
            const float* p = eWhh + (size_t)row * HDIM + kt * 32 + g16 * 8;
            f32x4 v0 = *(const f32x4*)p;
            f32x4 v1 = *(const f32x4*)(p + 4);
#pragma unroll
            for (int e = 0; e < 4; ++e) {
                short hi = f2bf(v0[e]);
                a_hi[tt][kt][e] = hi;
                a_lo[tt][kt][e] = f2bf(v0[e] - bf2f(hi));
            }
#pragma unroll
            for (int e = 0; e < 4; ++e) {
                short hi = f2bf(v1[e]);
                a_hi[tt][kt][4 + e] = hi;
                a_lo[tt][kt][4 + e] = f2bf(v1[e] - bf2f(hi));
            }
        }
    }

    // ---- xW A-fragments: same row permutation; K=8: e<7 Wih, e==7 bias ----
    bf16x8 axh[2], axl[2];
#pragma unroll
    for (int tt = 0; tt < 2; ++tt) {
        const int t = 2 * wid + tt;
        const int row = (m & 3) * 64 + 4 * t + (m >> 2);
        if (g16 == 0) {
#pragma unroll
            for (int e = 0; e < 8; ++e) {
                float v = (e < 7) ? eWih[row * INDIM + e] : (ebih[row] + ebhh[row]);
                short hi = f2bf(v);
                axh[tt][e] = hi;
                axl[tt][e] = f2bf(v - bf2f(hi));
            }
        } else {
#pragma unroll
            for (int e = 0; e < 8; ++e) { axh[tt][e] = 0; axl[tt][e] = 0; }
        }
    }

    // ---- init: step 0 reads h parity buffer 1; zero stub ----
    lds_hh[1][wid][lane] = 0;
    if (tid < 8) lds_xzero[tid] = 0;
    float c_reg = 0.0f;          // c for (b_act, u_act)

    // ---- x chunk loader (bf16 hi/lo RNE split; k==7 slot = 1.0) ----
    auto load_x_chunk = [&](int xbuf, int s0) {
        for (int i = tid; i < NBT * CHUNK * 8; i += 512) {
            int b = i >> 8;          // CHUNK*8 == 256 per batch
            int r = i & 255;
            int ss = r >> 3;
            int k = r & 7;
            float v = (k < 7) ? x[((size_t)(b0 + b) * SEQ + (s0 + ss)) * INDIM + k] : 1.0f;
            short hi = f2bf(v);
            lds_xbh[xbuf][ss][b][k] = hi;
            lds_xbl[xbuf][ss][b][k] = f2bf(v - bf2f(hi));
        }
    };

    // ---- xW GEMM for 4-step chunk j2 -> lds_px[j2&1] (needs x staged) ----
    auto compute_xw = [&](int j2) {
        const int sbase = 4 * j2;
        const int xbuf  = (sbase >> 5) & 1;
        const int sr0   = sbase & 31;
        const int col16 = lane & 15;
        const int pxb   = j2 & 1;
        bf16x8 bxh[2], bxl[2];
#pragma unroll
        for (int n = 0; n < 2; ++n) {
            const int srow = sr0 + 2 * n + (col16 >> 3);
            const short* ph = (g16 == 0) ? &lds_xbh[xbuf][srow][lane & 7][0] : &lds_xzero[0];
            const short* pl = (g16 == 0) ? &lds_xbl[xbuf][srow][lane & 7][0] : &lds_xzero[0];
            bxh[n] = *(const bf16x8*)ph;
            bxl[n] = *(const bf16x8*)pl;
        }
#pragma unroll
        for (int tt = 0; tt < 2; ++tt) {
#pragma unroll
            for (int n = 0; n < 2; ++n) {
                f32x4 p = {0, 0, 0, 0};
                p = __builtin_amdgcn_mfma_f32_16x16x32_bf16(axh[tt], bxh[n], p, 0, 0, 0);
                p = __builtin_amdgcn_mfma_f32_16x16x32_bf16(axl[tt], bxh[n], p, 0, 0, 0);
                p = __builtin_amdgcn_mfma_f32_16x16x32_bf16(axh[tt], bxl[n], p, 0, 0, 0);
                const int sl = 2 * n + (col16 >> 3);
                const int u  = 4 * (2 * wid + tt) + (lane >> 4);
                *(f32x4*)&lds_px[pxb][sl][lane & 7][u * 4] = p;
            }
        }
    };

    // ---- prologue: stage x chunk 0, compute px chunk 0 ----
    load_x_chunk(0, 0);
    __syncthreads();
    compute_xw(0);
    __syncthreads();

    // ================= encoder: 512 serial steps, ONE barrier each =================
    for (int s = 0; s < SEQ; ++s) {
        const int cs  = s & (CHUNK - 1);
        const int rb  = (s & 1) ^ 1;   // h read-parity
        const int wb  = s & 1;         // h write-parity

        // ---- px prefetch for THIS step: issue first, use last ----
        f32x4 px4 = *(const f32x4*)&lds_px[(s >> 2) & 1][s & 3][b_act][u_act * 4];

        // ---- B fragments: 2 b128 reads of single-bf16 h ----
        bf16x8 bh[2];
#pragma unroll
        for (int kt = 0; kt < 2; ++kt)
            bh[kt] = *(const bf16x8*)&lds_hh[rb][b_act][kt * 32 + g16 * 8];

        // ---- main MFMA: 2 tiles x (2 kt x 2-pass W-split) = 8, two chains ----
        f32x4 acc0 = {0, 0, 0, 0}, acc1 = {0, 0, 0, 0};
#pragma unroll
        for (int kt = 0; kt < 2; ++kt) {
            acc0 = __builtin_amdgcn_mfma_f32_16x16x32_bf16(a_hi[0][kt], bh[kt], acc0, 0, 0, 0);
            acc1 = __builtin_amdgcn_mfma_f32_16x16x32_bf16(a_hi[1][kt], bh[kt], acc1, 0, 0, 0);
            acc0 = __builtin_amdgcn_mfma_f32_16x16x32_bf16(a_lo[0][kt], bh[kt], acc0, 0, 0, 0);
            acc1 = __builtin_amdgcn_mfma_f32_16x16x32_bf16(a_lo[1][kt], bh[kt], acc1, 0, 0, 0);
        }

        // ---- gates are the regs of the selected tile (4 cndmasks) ----
        float pre[4];
#pragma unroll
        for (int g = 0; g < 4; ++g) pre[g] = tsel ? acc1[g] : acc0[g];

        // ---- activation: one chain per lane, (b_act, u_act) ----
        {
#pragma unroll
            for (int g = 0; g < 4; ++g) pre[g] += px4[g];
            float ig = sigm(pre[0]), fg = sigm(pre[1]), gg = tanh_f(pre[2]), og = sigm(pre[3]);
            c_reg = fg * c_reg + ig * gg;
            float h = og * tanh_f(c_reg);
            lds_hh[wb][b_act][u_act] = f2bf(h);   // single RNE bf16
            if (s + 1 == SEQ) {
                lds_hf[b_act][u_act] = h;
                lds_cf[b_act][u_act] = c_reg;
            }
        }

        // ---- xW for the NEXT 4-chunk: off act's issue path ----
        if ((s & 3) == 0 && s + 4 < SEQ) compute_xw((s >> 2) + 1);

        // ---- prefetch next x chunk ----
        if (cs == 0 && s + CHUNK < SEQ) {
            load_x_chunk(((s >> 5) & 1) ^ 1, s + CHUNK);
        }
        __syncthreads();   // h[wb] + px published for next step
    }
    // lds_hf/lds_cf hold h_enc/c_enc in (b, j) layout

    // ====== decoder gbase = b + h_enc @ dW_hh.T (fp32, one-time, 8 batches) ======
    {
        const int row = tid & 255;        // gate-matrix row
        const int gh  = tid >> 8;         // 0 -> batches 0-3, 1 -> batches 4-7
        float4 dwhh[16];
#pragma unroll
        for (int m4 = 0; m4 < 16; ++m4)
            dwhh[m4] = *reinterpret_cast<const float4*>(&dWhh[row * HDIM + m4 * 4]);
        const float dbias = dbih[row] + dbhh[row];

        float accd[4];
#pragma unroll
        for (int b = 0; b < 4; ++b) accd[b] = dbias;
#pragma unroll
        for (int m4 = 0; m4 < 16; ++m4) {
            const float4 w = dwhh[m4];
            float4 hv[4];
#pragma unroll
            for (int b = 0; b < 4; ++b)
                hv[b] = *reinterpret_cast<const float4*>(&lds_hf[gh * 4 + b][m4 * 4]);
#pragma unroll
            for (int b = 0; b < 4; ++b) accd[b] = fmaf(hv[b].x, w.x, accd[b]);
#pragma unroll
            for (int b = 0; b < 4; ++b) accd[b] = fmaf(hv[b].y, w.y, accd[b]);
#pragma unroll
            for (int b = 0; b < 4; ++b) accd[b] = fmaf(hv[b].z, w.z, accd[b]);
#pragma unroll
            for (int b = 0; b < 4; ++b) accd[b] = fmaf(hv[b].w, w.w, accd[b]);
        }
#pragma unroll
        for (int b = 0; b < 4; ++b) lds_g[gh * 4 + b][row] = accd[b];
    }
    __syncthreads();

    // ================= decoder: wave = one batch (8 waves, 8 batches) =================
    {
        const int b = wid, j = lane;
        const float c_e = lds_cf[b][j];
        const float gb0 = lds_g[b][j];
        const float gb1 = lds_g[b][HDIM + j];
        const float gb2 = lds_g[b][2 * HDIM + j];
        const float gb3 = lds_g[b][3 * HDIM + j];

        const float w00 = dWih[(0 * HDIM + j) * QDIM + 0], w01 = dWih[(0 * HDIM + j) * QDIM + 1], w02 = dWih[(0 * HDIM + j) * QDIM + 2];
        const float w10 = dWih[(1 * HDIM + j) * QDIM + 0], w11 = dWih[(1 * HDIM + j) * QDIM + 1], w12 = dWih[(1 * HDIM + j) * QDIM + 2];
        const float w20 = dWih[(2 * HDIM + j) * QDIM + 0], w21 = dWih[(2 * HDIM + j) * QDIM + 1], w22 = dWih[(2 * HDIM + j) * QDIM + 2];
        const float w30 = dWih[(3 * HDIM + j) * QDIM + 0], w31 = dWih[(3 * HDIM + j) * QDIM + 1], w32 = dWih[(3 * HDIM + j) * QDIM + 2];
        const float ow0 = oW[0 * HDIM + j], ow1 = oW[1 * HDIM + j], ow2 = oW[2 * HDIM + j];
        const float ob0 = obv[0], ob1 = obv[1], ob2 = obv[2];

        float y0 = 0.0f, y1 = 0.0f, y2 = 0.0f;
        float* outp = out + (size_t)(b0 + b) * TDEC * QDIM;

        for (int t = 0; t < TDEC; ++t) {
            float g0 = gb0 + y0 * w00 + y1 * w01 + y2 * w02;
            float g1 = gb1 + y0 * w10 + y1 * w11 + y2 * w12;
            float g2 = gb2 + y0 * w20 + y1 * w21 + y2 * w22;
            float g3 = gb3 + y0 * w30 + y1 * w31 + y2 * w32;
            float ig = sigm(g0), fg = sigm(g1), gg = tanh_f(g2), og = sigm(g3);
            float c = fg * c_e + ig * gg;
            float h = og * tanh_f(c);
            float r0 = h * ow0, r1 = h * ow1, r2 = h * ow2;
#pragma unroll
            for (int d = 1; d < 64; d <<= 1) {
                r0 += __shfl_xor(r0, d);
                r1 += __shfl_xor(r1, d);
                r2 += __shfl_xor(r2, d);
            }
            y0 = r0 + ob0;
            y1 = r1 + ob1;
            y2 = r2 + ob2;
            if (j < QDIM) outp[t * QDIM + j] = (j == 0) ? y0 : (j == 1) ? y1 : y2;
        }
    }
}

extern "C" void kernel_launch(void* const* d_in, const int* in_sizes, int n_in,
                              void* d_out, int out_size, void* d_ws, size_t ws_size,
                              hipStream_t stream) {
    (void)in_sizes; (void)n_in; (void)d_ws; (void)ws_size; (void)out_size;
    const float* x    = (const float*)d_in[0];
    const float* eWih = (const float*)d_in[1];
    const float* eWhh = (const float*)d_in[2];
    const float* ebih = (const float*)d_in[3];
    const float* ebhh = (const float*)d_in[4];
    const float* dWih = (const float*)d_in[5];
    const float* dWhh = (const float*)d_in[6];
    const float* dbih = (const float*)d_in[7];
    const float* dbhh = (const float*)d_in[8];
    const float* oW   = (const float*)d_in[9];
    const float* obv  = (const float*)d_in[10];
    float* out = (float*)d_out;

    const int B = 2048;
    dim3 grid(B / NBT), block(512);
    enc_dec_kernel<<<grid, block, 0, stream>>>(x, eWih, eWhh, ebih, ebhh,
                                               dWih, dWhh, dbih, dbhh, oW, obv, out);
}